// Round 6
// baseline (387.086 us; speedup 1.0000x reference)
//
#include <hip/hip_runtime.h>

// Problem constants (match reference)
constexpr int N  = 100000;   // nodes
constexpr int E  = 1600000;  // edges
constexpr int H  = 128;      // hidden
constexpr int NB = 4096;     // root pairs
constexpr int HOPS = 3;
constexpr int EPT = 8;       // edges per thread in E-scans (MLP)

// Swizzled converted-weight buffer (element offsets into whi/wlo ushort arrays).
constexpr int WOFF_L1  = 0;                      // numC=8,  numT=8  (K=256)
constexpr int WOFF_GAT = 32768;                  // 3 x numC=8,  numT=4
constexpr int WOFF_CAT = 81920;                  // 3 x numC=32, numT=12 (gate-perm)
constexpr int WOFF_L2  = 671744;                 // numC=8,  numT=4
constexpr int WTOT     = 688128;

// ---------------- workspace layout (byte offsets, 256B aligned) ---------------
constexpr size_t ALIGN = 256;
constexpr size_t alup(size_t x) { return (x + ALIGN - 1) & ~(ALIGN - 1); }

constexpr size_t OFF_X       = 0;                                        // repurposed (below)
constexpr size_t OFF_SSRC    = alup(OFF_X + (size_t)N * H * 4);          // [3][N] f32
constexpr size_t OFF_SDST    = alup(OFF_SSRC + (size_t)3 * N * 4);       // [3][N] f32
constexpr size_t OFF_WVEC    = alup(OFF_SDST + (size_t)3 * N * 4);       // [6][128] f32
constexpr size_t OFF_SELMAP  = alup(OFF_WVEC + 6 * H * 4);               // [N] int
constexpr size_t OFF_NODELST = alup(OFF_SELMAP + (size_t)N * 4);         // [4096] int
constexpr size_t OFF_CNT     = alup(OFF_NODELST + NB * 4);               // [64] int
constexpr size_t OFF_DEG     = alup(OFF_CNT + 256);                      // [4096] int
constexpr size_t OFF_OFFS    = alup(OFF_DEG + NB * 4);                   // [4097] int
constexpr size_t OFF_CURSOR  = alup(OFF_OFFS + (NB + 1) * 4);            // [4096] int
constexpr size_t OFF_ESORT   = alup(OFF_CURSOR + NB * 4);                // [E] int
constexpr size_t OFF_AGGXH   = alup(OFF_ESORT + (size_t)E * 4);          // [3][4096][128] us
constexpr size_t OFF_AGGXL   = alup(OFF_AGGXH + (size_t)3 * NB * H * 2);
constexpr size_t OFF_XSH     = alup(OFF_AGGXL + (size_t)3 * NB * H * 2); // [4096][128] us
constexpr size_t OFF_XSL     = alup(OFF_XSH + (size_t)NB * H * 2);
constexpr size_t OFF_HH      = alup(OFF_XSL + (size_t)NB * H * 2);       // h pair
constexpr size_t OFF_HL      = alup(OFF_HH + (size_t)NB * H * 2);
constexpr size_t OFF_CBUF    = alup(OFF_HL + (size_t)NB * H * 2);        // [4096][128] f32
constexpr size_t OFF_L2OUT   = alup(OFF_CBUF + (size_t)NB * H * 4);      // [4096][128] f32
constexpr size_t OFF_WHI     = alup(OFF_L2OUT + (size_t)NB * H * 4);     // [WTOT] us
constexpr size_t OFF_WLO     = alup(OFF_WHI + (size_t)WTOT * 2);         // [WTOT] us

// Repurposed old-x region (51.2 MB): raw-feature aggregation + folded score vecs
constexpr size_t OFF_AGGRAW  = OFF_X;                                    // [3*4096][256] f32 (12.6MB)
constexpr size_t OFF_WV2     = OFF_X + (size_t)16 * 1024 * 1024;         // [6][256] f32
constexpr size_t OFF_C2      = OFF_WV2 + 6 * 256 * 4;                    // [6] f32

__device__ __forceinline__ float lrelu(float v) { return v > 0.f ? v : 0.2f * v; }
__device__ __forceinline__ float sigmoidf_(float v) { return 1.f / (1.f + __expf(-v)); }

__device__ __forceinline__ unsigned short f2bf(float f) {
  unsigned u = __float_as_uint(f);
  unsigned r = (u + 0x7FFFu + ((u >> 16) & 1u)) >> 16;
  return (unsigned short)r;
}
__device__ __forceinline__ float bf2f(unsigned short h) {
  return __uint_as_float((unsigned)h << 16);
}
__device__ __forceinline__ void split_rne(float f, unsigned short& hi, unsigned short& lo) {
  unsigned short hh = f2bf(f);
  hi = hh;
  lo = f2bf(f - bf2f(hh));
}
// 4-op truncation split (GEMM hot path); pointer outs (vector elems can't bind refs)
__device__ __forceinline__ void split_trunc(float f, short* hi, short* lo) {
  unsigned u = __float_as_uint(f);
  *hi = (short)(u >> 16);
  float r = f - __uint_as_float(u & 0xFFFF0000u);
  *lo = (short)(__float_as_uint(r) >> 16);
}

typedef short bf16x8 __attribute__((ext_vector_type(8)));
typedef float f32x4  __attribute__((ext_vector_type(4)));

#define MFMA3(ACC, AH, AL, BH, BL)                                               \
  ACC = __builtin_amdgcn_mfma_f32_16x16x32_bf16(AH, BH, ACC, 0, 0, 0);           \
  ACC = __builtin_amdgcn_mfma_f32_16x16x32_bf16(AH, BL, ACC, 0, 0, 0);           \
  ACC = __builtin_amdgcn_mfma_f32_16x16x32_bf16(AL, BH, ACC, 0, 0, 0);

// ---------------- init: replaces memsets ---------------------------------------
__global__ void init_ws(int* __restrict__ sel_map, int* __restrict__ deg,
                        int* __restrict__ cursor, int* __restrict__ cnt,
                        float* __restrict__ cbuf, unsigned short* __restrict__ hh,
                        unsigned short* __restrict__ hl, int* __restrict__ need_flag) {
  int i = blockIdx.x * 256 + threadIdx.x;
  int stride = gridDim.x * 256;
  for (int n = i; n < N; n += stride) { sel_map[n] = -1; need_flag[n] = 0; }
  for (int n = i; n < NB; n += stride) { deg[n] = 0; cursor[n] = 0; }
  if (i < 64) cnt[i] = 0;
  for (int n = i; n < NB * H; n += stride) { cbuf[n] = 0.f; hh[n] = 0; hl[n] = 0; }
}

// ---------------- prep: wvec + weight convert to swizzled fragment tiles -------
__global__ void prep_kernel(const float* __restrict__ gat_W,
                            const float* __restrict__ a_src,
                            const float* __restrict__ a_dst,
                            float* __restrict__ wvec,
                            const float* __restrict__ lin1_W,
                            const float* __restrict__ Wih,
                            const float* __restrict__ Whh,
                            const float* __restrict__ lin2_W,
                            unsigned short* __restrict__ whi,
                            unsigned short* __restrict__ wlo) {
  if (blockIdx.x < 6) {
    int i = blockIdx.x >> 1, which = blockIdx.x & 1;
    int k = threadIdx.x;
    __shared__ float av[H];
    if (k < H) av[k] = which ? a_dst[i * H + k] : a_src[i * H + k];
    __syncthreads();
    if (k >= H) return;
    const float* Wr = gat_W + (size_t)i * H * H + (size_t)k * H;
    float s = 0.f;
    #pragma unroll 8
    for (int j = 0; j < H; j++) s = fmaf(Wr[j], av[j], s);
    wvec[(i * 2 + which) * H + k] = s;
    return;
  }
  int idx = (blockIdx.x - 6) * 256 + threadIdx.x;
  if (idx >= WTOT) return;
  float v;
  if (idx < WOFF_GAT) {                      // lin1: numC=8, K=256
    int rel = idx;
    int e = rel & 7, lane = (rel >> 3) & 63, tile = rel >> 9;
    int nl = lane & 15, quad = lane >> 4;
    int c = tile & 7, t = tile >> 3;
    int n = c * 16 + nl, k = t * 32 + quad * 8 + e;
    v = lin1_W[k * 128 + n];
  } else if (idx < WOFF_CAT) {               // gat: 3 x numC=8, K=128
    int rel = idx - WOFF_GAT;
    int hop = rel / 16384; rel %= 16384;
    int e = rel & 7, lane = (rel >> 3) & 63, tile = rel >> 9;
    int nl = lane & 15, quad = lane >> 4;
    int c = tile & 7, t = tile >> 3;
    int n = c * 16 + nl, k = t * 32 + quad * 8 + e;
    v = gat_W[hop * 16384 + k * 128 + n];
  } else if (idx < WOFF_L2) {                // CAT: 3 x numC=32, K=384, gate-perm
    int rel = idx - WOFF_CAT;
    int hop = rel / 196608; rel %= 196608;
    int e = rel & 7, lane = (rel >> 3) & 63, tile = rel >> 9;
    int nl = lane & 15, quad = lane >> 4;
    int c = tile & 31, t = tile >> 5;
    int ftile = c >> 2, g = c & 3;           // virtual col tile -> (feature-tile, gate)
    int col = g * 128 + ftile * 16 + nl;     // original column in [Wih;Whh]
    int k = t * 32 + quad * 8 + e;
    v = (k < 256) ? Wih[hop * 131072 + k * 512 + col]
                  : Whh[hop * 65536 + (k - 256) * 512 + col];
  } else {                                   // lin2: numC=8, K=128
    int rel = idx - WOFF_L2;
    int e = rel & 7, lane = (rel >> 3) & 63, tile = rel >> 9;
    int nl = lane & 15, quad = lane >> 4;
    int c = tile & 7, t = tile >> 3;
    int n = c * 16 + nl, k = t * 32 + quad * 8 + e;
    v = lin2_W[k * 128 + n];
  }
  unsigned short hh, ll;
  split_rne(v, hh, ll);
  whi[idx] = hh;
  wlo[idx] = ll;
}

// ---------------- prep2: fold lin1 into score vectors --------------------------
// wv2[v] = W1 @ wvec[v]  (256-dim), c2[v] = b1 . wvec[v].  Then
// s = x . wvec = cat . wv2 + c2  — scores need NO lin1 GEMM over sources.
__global__ void prep2_kernel(const float* __restrict__ lin1_W,
                             const float* __restrict__ lin1_b,
                             const float* __restrict__ wvec,
                             float* __restrict__ wv2, float* __restrict__ c2) {
  int v = blockIdx.x;          // 0..5
  int j = threadIdx.x;         // 0..255 (row of W1)
  __shared__ float wv[H];
  if (j < H) wv[j] = wvec[v * H + j];
  __syncthreads();
  const float* Wr = lin1_W + (size_t)j * H;
  float s = 0.f;
  #pragma unroll 8
  for (int m = 0; m < H; m++) s = fmaf(Wr[m], wv[m], s);
  wv2[v * 256 + j] = s;
  if (j == 0) {
    float cc = 0.f;
    for (int m = 0; m < H; m++) cc = fmaf(lin1_b[m], wv[m], cc);
    c2[v] = cc;
  }
}

// ---------------- roots: mark + compact-id assign ------------------------------
__global__ void roots_assign(const int* __restrict__ root, const int* __restrict__ aggp,
                             int* __restrict__ sel_map, int* __restrict__ node_list,
                             int* __restrict__ cnt, int* __restrict__ need_flag) {
  int b = blockIdx.x * 256 + threadIdx.x;
  if (b >= NB) return;
  int node = root[2 * b + (aggp[0] ? 0 : 1)];
  need_flag[node] = 1;                       // plain store, idempotent
  int old = atomicCAS(&sel_map[node], -1, -2);
  if (old == -1) {
    int c = atomicAdd(cnt, 1);
    sel_map[node] = c;
    node_list[c] = node;
  }
}

// ---------------- edge CSR by destination: EPT-batched for MLP -----------------
__global__ void count_edges(const int* __restrict__ ei, const int* __restrict__ sel_map,
                            int* __restrict__ deg) {
  const int T = gridDim.x * 256;
  const int base = blockIdx.x * 256 + threadIdx.x;
  int dn[EPT];
  #pragma unroll
  for (int k = 0; k < EPT; k++) {
    int e = base + k * T;
    dn[k] = (e < E) ? ei[E + e] : -1;
  }
  #pragma unroll
  for (int k = 0; k < EPT; k++) {
    if (dn[k] >= 0) dn[k] = sel_map[dn[k]];
  }
  #pragma unroll
  for (int k = 0; k < EPT; k++) {
    if (dn[k] >= 0) atomicAdd(&deg[dn[k]], 1);
  }
}

__global__ __launch_bounds__(1024)
void scan_kernel(const int* __restrict__ deg, int* __restrict__ offs) {
  __shared__ int part[1024];
  int t = threadIdx.x;
  int base = t * 4;
  int v0 = deg[base], v1 = deg[base + 1], v2 = deg[base + 2], v3 = deg[base + 3];
  int s = v0 + v1 + v2 + v3;
  part[t] = s;
  __syncthreads();
  for (int off = 1; off < 1024; off <<= 1) {
    int tmp = (t >= off) ? part[t - off] : 0;
    __syncthreads();
    part[t] += tmp;
    __syncthreads();
  }
  int run = part[t] - s;
  offs[base] = run; run += v0;
  offs[base + 1] = run; run += v1;
  offs[base + 2] = run; run += v2;
  offs[base + 3] = run;
  if (t == 1023) offs[NB] = part[1023];
}

__global__ void scatter_edges2(const int* __restrict__ ei, const int* __restrict__ sel_map,
                               const int* __restrict__ offs, int* __restrict__ cursor,
                               int* __restrict__ es_sorted, int* __restrict__ need_flag) {
  const int T = gridDim.x * 256;
  const int base = blockIdx.x * 256 + threadIdx.x;
  int dn[EPT], sn[EPT];
  #pragma unroll
  for (int k = 0; k < EPT; k++) {
    int e = base + k * T;
    dn[k] = (e < E) ? ei[E + e] : -1;
  }
  #pragma unroll
  for (int k = 0; k < EPT; k++) {
    if (dn[k] >= 0) dn[k] = sel_map[dn[k]];
  }
  #pragma unroll
  for (int k = 0; k < EPT; k++) {
    int e = base + k * T;
    if (dn[k] >= 0) sn[k] = ei[e];
  }
  #pragma unroll
  for (int k = 0; k < EPT; k++) {
    if (dn[k] >= 0) {
      int p = atomicAdd(&cursor[dn[k]], 1);
      es_sorted[offs[dn[k]] + p] = sn[k];
      need_flag[sn[k]] = 1;                  // plain store, idempotent (no RMW)
    }
  }
}

// ---------------- needed-set compaction (wave-ballot, ~1.5K atomics total) -----
__global__ void compact_need(const int* __restrict__ need_flag,
                             int* __restrict__ need_list, int* __restrict__ need_cnt) {
  int i = blockIdx.x * 256 + threadIdx.x;
  bool f = (i < N) && (need_flag[i] != 0);
  unsigned long long mask = __ballot(f);
  int lane = threadIdx.x & 63;
  int wcnt = __popcll(mask);
  int base = 0;
  if (lane == 0 && wcnt > 0) base = atomicAdd(need_cnt, wcnt);
  base = __shfl(base, 0);
  if (f) {
    int prefix = __popcll(mask & ((1ull << lane) - 1ull));
    need_list[base + prefix] = i;
  }
}

// ---------------- score pass: s = cat . wv2 + c2 over needed rows --------------
// Pure gather + 6 dots: no B-tiles, no MFMA, ~40 VGPR, 6KB LDS -> max TLP.
// 16 rows/block (16 lanes per row, 4 float4 loads/lane). This is the
// concurrency-vs-request-rate diagnostic for the 1 TB/s wall.
__global__ __launch_bounds__(256)
void score_pass(const float* __restrict__ a0, const float* __restrict__ a1,
                const float* __restrict__ wv2, const float* __restrict__ c2,
                float* __restrict__ s_src, float* __restrict__ s_dst,
                const int* __restrict__ need_list, const int* __restrict__ need_cnt) {
  const int nneed = need_cnt[0];
  if (blockIdx.x * 16 >= nneed) return;
  __shared__ float Ws[6 * 256];
  __shared__ float C2s[6];
  const int t = threadIdx.x, lane = t & 63, wave = t >> 6;
  const int nl = lane & 15;
  #pragma unroll
  for (int v = 0; v < 6; v++) Ws[v * 256 + t] = wv2[v * 256 + t];
  if (t < 6) C2s[t] = c2[t];
  __syncthreads();

  int r = blockIdx.x * 16 + wave * 4 + (lane >> 4);
  int row = (r < nneed) ? need_list[r] : -1;
  int rc = (row < 0) ? 0 : row;
  const float* src = (nl < 8) ? (a0 + (size_t)rc * H + nl * 16)
                              : (a1 + (size_t)rc * H + (nl - 8) * 16);
  float4 va[4];
  #pragma unroll
  for (int q = 0; q < 4; q++) va[q] = ((const float4*)src)[q];

  float p[6] = {0.f, 0.f, 0.f, 0.f, 0.f, 0.f};
  #pragma unroll
  for (int q = 0; q < 4; q++) {
    float4 v4 = va[q];
    #pragma unroll
    for (int v = 0; v < 6; v++) {
      float4 w4 = *(const float4*)&Ws[v * 256 + nl * 16 + q * 4];
      p[v] = fmaf(v4.x, w4.x, p[v]);
      p[v] = fmaf(v4.y, w4.y, p[v]);
      p[v] = fmaf(v4.z, w4.z, p[v]);
      p[v] = fmaf(v4.w, w4.w, p[v]);
    }
  }
  #pragma unroll
  for (int m = 1; m < 16; m <<= 1)
    #pragma unroll
    for (int v = 0; v < 6; v++) p[v] += __shfl_xor(p[v], m);
  if (nl == 0 && row >= 0) {
    #pragma unroll
    for (int h3 = 0; h3 < 3; h3++) {
      s_src[h3 * N + row] = p[2 * h3 + 0] + C2s[2 * h3 + 0];
      s_dst[h3 * N + row] = p[2 * h3 + 1] + C2s[2 * h3 + 1];
    }
  }
}

// ---------------- per-destination GAT softmax aggregation (RAW features) -------
// agg_raw[h][c][0:256] = sum_e alpha_e cat[src_e]  (f32; linearity: lin1 applied
// later on 4096 rows instead of 50K). 256 threads = 256 features.
__global__ __launch_bounds__(256)
void gat_node_kernel(const int* __restrict__ node_list, const int* __restrict__ cntp,
                     const int* __restrict__ offs, const int* __restrict__ es_sorted,
                     const float* __restrict__ a0, const float* __restrict__ a1,
                     const float* __restrict__ s_src, const float* __restrict__ s_dst,
                     float* __restrict__ agg_raw) {
  int c = blockIdx.x;
  if (c >= cntp[0]) return;
  int t = threadIdx.x;
  int n = node_list[c];
  float sd0 = s_dst[0 * N + n], sd1 = s_dst[1 * N + n], sd2 = s_dst[2 * N + n];
  int e0 = offs[c], e1 = offs[c + 1];
  float m0 = -1e30f, m1 = -1e30f, m2 = -1e30f;
  for (int e = e0 + t; e < e1; e += 256) {
    int s = es_sorted[e];
    m0 = fmaxf(m0, lrelu(s_src[0 * N + s] + sd0));
    m1 = fmaxf(m1, lrelu(s_src[1 * N + s] + sd1));
    m2 = fmaxf(m2, lrelu(s_src[2 * N + s] + sd2));
  }
  __shared__ float red[3][256];
  red[0][t] = m0; red[1][t] = m1; red[2][t] = m2;
  __syncthreads();
  for (int s2 = 128; s2 > 0; s2 >>= 1) {
    if (t < s2) {
      red[0][t] = fmaxf(red[0][t], red[0][t + s2]);
      red[1][t] = fmaxf(red[1][t], red[1][t + s2]);
      red[2][t] = fmaxf(red[2][t], red[2][t + s2]);
    }
    __syncthreads();
  }
  m0 = red[0][0]; m1 = red[1][0]; m2 = red[2][0];
  float u0 = 0.f, u1 = 0.f, u2 = 0.f, z0 = 0.f, z1 = 0.f, z2 = 0.f;
  for (int e = e0; e < e1; e++) {
    int s = es_sorted[e];
    float xs = (t < 128) ? a0[(size_t)s * H + t] : a1[(size_t)s * H + (t - 128)];
    float ex0 = __expf(lrelu(s_src[0 * N + s] + sd0) - m0);
    float ex1 = __expf(lrelu(s_src[1 * N + s] + sd1) - m1);
    float ex2 = __expf(lrelu(s_src[2 * N + s] + sd2) - m2);
    z0 += ex0; z1 += ex1; z2 += ex2;
    u0 = fmaf(ex0, xs, u0); u1 = fmaf(ex1, xs, u1); u2 = fmaf(ex2, xs, u2);
  }
  size_t cb = (size_t)c * 256 + t;
  bool any = e1 > e0;
  agg_raw[0 * ((size_t)NB * 256) + cb] = any ? u0 / z0 : 0.f;
  agg_raw[1 * ((size_t)NB * 256) + cb] = any ? u1 / z1 : 0.f;
  agg_raw[2 * ((size_t)NB * 256) + cb] = any ? u2 / z2 : 0.f;
}

// ---------------- unified lin1 GEMM: 12288 agg rows + 4096 root rows -----------
// Rows 0..12287: agg_raw (dense 256-f32 rows; +b1 only if the dest has edges,
// keeping isolated-node aggx == 0 bit-compatible). Rows 12288..16383: root-node
// cat gather -> xs staging (+b1 always). 16 rows/wave, 64/block, grid 256.
__global__ __launch_bounds__(256)
void gemm_unified(const float* __restrict__ agg_raw,
                  const float* __restrict__ a0, const float* __restrict__ a1,
                  const int* __restrict__ node_list, const int* __restrict__ cntp,
                  const int* __restrict__ offs,
                  const unsigned short* __restrict__ Bth,
                  const unsigned short* __restrict__ Btl,
                  const float* __restrict__ bias,
                  unsigned short* __restrict__ aggxh, unsigned short* __restrict__ aggxl,
                  unsigned short* __restrict__ xsh, unsigned short* __restrict__ xsl) {
  const int t = threadIdx.x, lane = t & 63, wave = t >> 6;
  const int nl = lane & 15, quad = lane >> 4;
  const int rt = blockIdx.x * 64 + wave * 16;
  const int cnt = cntp[0];

  int gr = rt + nl;
  const float *pA, *pB;
  if (gr < 12288) {
    pA = agg_raw + (size_t)gr * 256;
    pB = pA + 128;
  } else {
    int cc = gr - 12288;
    int node = (cc < cnt) ? node_list[cc] : 0;
    pA = a0 + (size_t)node * H;
    pB = a1 + (size_t)node * H;
  }

  f32x4 acc[8];
  #pragma unroll
  for (int c = 0; c < 8; c++) acc[c] = (f32x4){0.f, 0.f, 0.f, 0.f};

  #pragma unroll
  for (int kt = 0; kt < 8; kt++) {
    const float* p = ((kt < 4) ? pA : pB) + (kt & 3) * 32 + quad * 8;
    bf16x8 ahi, alo;
    {
      float4 v0 = *(const float4*)p;
      float4 v1 = *(const float4*)(p + 4);
      float af[8] = {v0.x, v0.y, v0.z, v0.w, v1.x, v1.y, v1.z, v1.w};
      #pragma unroll
      for (int j = 0; j < 8; j++) {
        short h_, l_;
        split_trunc(af[j], &h_, &l_);
        ahi[j] = h_;
        alo[j] = l_;
      }
    }
    #pragma unroll
    for (int c = 0; c < 8; c++) {
      size_t boff = ((size_t)(kt * 8 + c) * 64 + lane) * 8;   // coalesced frag tile
      bf16x8 bh = *(const bf16x8*)(Bth + boff);
      bf16x8 bl = *(const bf16x8*)(Btl + boff);
      MFMA3(acc[c], ahi, alo, bh, bl);
    }
  }

  float bv[8];
  #pragma unroll
  for (int c = 0; c < 8; c++) bv[c] = bias[c * 16 + nl];

  #pragma unroll
  for (int r = 0; r < 4; r++) {
    int g2 = rt + quad * 4 + r;
    if (g2 < 12288) {
      int cc = g2 & 4095, h = g2 >> 12;
      bool he = offs[cc + 1] > offs[cc];
      size_t base = (size_t)h * NB * H + (size_t)cc * H;
      #pragma unroll
      for (int c = 0; c < 8; c++) {
        float val = acc[c][r] + (he ? bv[c] : 0.f);
        unsigned short vh, vl;
        split_rne(val, vh, vl);
        aggxh[base + c * 16 + nl] = vh;
        aggxl[base + c * 16 + nl] = vl;
      }
    } else {
      int cc = g2 - 12288;
      size_t base = (size_t)cc * H;
      #pragma unroll
      for (int c = 0; c < 8; c++) {
        float val = acc[c][r] + bv[c];
        unsigned short vh, vl;
        split_rne(val, vh, vl);
        xsh[base + c * 16 + nl] = vh;
        xsl[base + c * 16 + nl] = vl;
      }
    }
  }
}

// ---------------- fused hop: 16-row blocks (grid 256), swizzled weights --------
// Wave w owns feature-tiles {2w, 2w+1} (32 features, all 4 gates each).
__global__ __launch_bounds__(256)
void hop_fused(const unsigned short* __restrict__ agh, const unsigned short* __restrict__ agl,
               const unsigned short* __restrict__ gWh, const unsigned short* __restrict__ gWl,
               const float* __restrict__ gbias,
               const unsigned short* __restrict__ x1h, const unsigned short* __restrict__ x1l,
               const unsigned short* __restrict__ CWh, const unsigned short* __restrict__ CWl,
               const float* __restrict__ lbias,
               float* __restrict__ cbuf, unsigned short* __restrict__ hh,
               unsigned short* __restrict__ hl,
               const unsigned short* __restrict__ L2h, const unsigned short* __restrict__ L2l,
               const float* __restrict__ lin2_b, float* __restrict__ l2out, int do_lin2) {
  __shared__ unsigned short Hh[16 * 136];
  __shared__ unsigned short Hl[16 * 136];
  const int t = threadIdx.x, lane = t & 63, wave = t >> 6;
  const int nl = lane & 15, quad = lane >> 4;
  const int r0 = blockIdx.x * 16;

  // ---- GEMM1: htmp = tanh(aggx @ gatW + b); wave: 16 rows x 32 cols
  f32x4 acc1[2];
  #pragma unroll
  for (int j = 0; j < 2; j++) acc1[j] = (f32x4){0.f, 0.f, 0.f, 0.f};
  #pragma unroll
  for (int kt = 0; kt < 4; kt++) {
    size_t aoff = (size_t)(r0 + nl) * H + kt * 32 + quad * 8;
    bf16x8 ah = *(const bf16x8*)(agh + aoff);
    bf16x8 al = *(const bf16x8*)(agl + aoff);
    #pragma unroll
    for (int j = 0; j < 2; j++) {
      size_t boff = ((size_t)(kt * 8 + 2 * wave + j) * 64 + lane) * 8;
      bf16x8 bh = *(const bf16x8*)(gWh + boff);
      bf16x8 bl = *(const bf16x8*)(gWl + boff);
      MFMA3(acc1[j], ah, al, bh, bl);
    }
  }
  #pragma unroll
  for (int j = 0; j < 2; j++) {
    int col = wave * 32 + j * 16 + nl;
    float bv = gbias[col];
    #pragma unroll
    for (int r = 0; r < 4; r++) {
      int rl = quad * 4 + r;
      float v = tanhf(acc1[j][r] + bv);
      unsigned short vh, vl2;
      split_rne(v, vh, vl2);
      Hh[rl * 136 + col] = vh;
      Hl[rl * 136 + col] = vl2;
    }
  }
  __syncthreads();

  // ---- GEMM2: permuted gates [16 x 384] @ [384 x 512]; wave: 8 col-tiles
  f32x4 acc2[8];
  #pragma unroll
  for (int j = 0; j < 8; j++) acc2[j] = (f32x4){0.f, 0.f, 0.f, 0.f};
  for (int kt = 0; kt < 12; kt++) {
    int kk = (kt & 3) * 32 + quad * 8;
    bf16x8 ah, al;
    if (kt < 4) {
      ah = *(const bf16x8*)&Hh[nl * 136 + kk];
      al = *(const bf16x8*)&Hl[nl * 136 + kk];
    } else {
      const unsigned short* ph = (kt < 8) ? x1h : hh;
      const unsigned short* pl = (kt < 8) ? x1l : hl;
      size_t aoff = (size_t)(r0 + nl) * H + kk;
      ah = *(const bf16x8*)(ph + aoff);
      al = *(const bf16x8*)(pl + aoff);
    }
    #pragma unroll
    for (int cc = 0; cc < 8; cc++) {
      size_t boff = ((size_t)(kt * 32 + 8 * wave + cc) * 64 + lane) * 8;
      bf16x8 bh = *(const bf16x8*)(CWh + boff);
      bf16x8 bl = *(const bf16x8*)(CWl + boff);
      MFMA3(acc2[cc], ah, al, bh, bl);
    }
  }
  __syncthreads();   // all LDS + global-h reads done before h/LDS writes below

  // ---- LSTM pointwise; lane has all 4 gates of its features
  #pragma unroll
  for (int ft = 0; ft < 2; ft++) {
    int f = (2 * wave + ft) * 16 + nl;
    float b_i = lbias[0 * 128 + f], b_f = lbias[1 * 128 + f];
    float b_g = lbias[2 * 128 + f], b_o = lbias[3 * 128 + f];
    #pragma unroll
    for (int r = 0; r < 4; r++) {
      int rl = quad * 4 + r;
      size_t id = (size_t)(r0 + rl) * H + f;
      float gi = acc2[ft * 4 + 0][r] + b_i;
      float gf = acc2[ft * 4 + 1][r] + b_f;
      float gg = acc2[ft * 4 + 2][r] + b_g;
      float go = acc2[ft * 4 + 3][r] + b_o;
      float cp = cbuf[id];
      float cn = sigmoidf_(gf) * cp + sigmoidf_(gi) * tanhf(gg);
      float hn = sigmoidf_(go) * tanhf(cn);
      cbuf[id] = cn;
      unsigned short vh, vl2;
      split_rne(hn, vh, vl2);
      hh[id] = vh;
      hl[id] = vl2;
      if (do_lin2) { Hh[rl * 136 + f] = vh; Hl[rl * 136 + f] = vl2; }
    }
  }

  if (!do_lin2) return;
  __syncthreads();
  // ---- GEMM3: lin2 on h; wave: 16 rows x 32 cols
  f32x4 acc3[2];
  #pragma unroll
  for (int j = 0; j < 2; j++) acc3[j] = (f32x4){0.f, 0.f, 0.f, 0.f};
  #pragma unroll
  for (int kt = 0; kt < 4; kt++) {
    int kk = kt * 32 + quad * 8;
    bf16x8 ah = *(const bf16x8*)&Hh[nl * 136 + kk];
    bf16x8 al = *(const bf16x8*)&Hl[nl * 136 + kk];
    #pragma unroll
    for (int j = 0; j < 2; j++) {
      size_t boff = ((size_t)(kt * 8 + 2 * wave + j) * 64 + lane) * 8;
      bf16x8 bh = *(const bf16x8*)(L2h + boff);
      bf16x8 bl = *(const bf16x8*)(L2l + boff);
      MFMA3(acc3[j], ah, al, bh, bl);
    }
  }
  #pragma unroll
  for (int j = 0; j < 2; j++) {
    int col = wave * 32 + j * 16 + nl;
    float bv = lin2_b[col];
    #pragma unroll
    for (int r = 0; r < 4; r++) {
      int row = r0 + quad * 4 + r;
      l2out[(size_t)row * H + col] = acc3[j][r] + bv;
    }
  }
}

// ---------------- output gather ------------------------------------------------
__global__ void scatter_out(const float* __restrict__ l2out, const int* __restrict__ sel_map,
                            const int* __restrict__ root, const int* __restrict__ aggp,
                            float* __restrict__ out) {
  int id = blockIdx.x * 256 + threadIdx.x;
  if (id >= NB * H) return;
  int b = id >> 7, f = id & 127;
  int node = root[2 * b + (aggp[0] ? 0 : 1)];
  int c = sel_map[node];
  out[id] = l2out[(size_t)c * H + f];
}

// ==============================================================================
extern "C" void kernel_launch(void* const* d_in, const int* in_sizes, int n_in,
                              void* d_out, int out_size, void* d_ws, size_t ws_size,
                              hipStream_t stream) {
  const float* node_feat = (const float*)d_in[0];
  const float* send_embd = (const float*)d_in[1];
  const int*   edge_idx  = (const int*)d_in[2];
  const int*   root_idx  = (const int*)d_in[3];
  const int*   aggp      = (const int*)d_in[4];
  const float* lin1_W    = (const float*)d_in[5];
  const float* lin1_b    = (const float*)d_in[6];
  const float* gat_W     = (const float*)d_in[7];
  const float* gat_asrc  = (const float*)d_in[8];
  const float* gat_adst  = (const float*)d_in[9];
  const float* gat_b     = (const float*)d_in[10];
  const float* lstm_Wih  = (const float*)d_in[11];
  const float* lstm_Whh  = (const float*)d_in[12];
  const float* lstm_b    = (const float*)d_in[13];
  const float* lin2_W    = (const float*)d_in[14];
  const float* lin2_b    = (const float*)d_in[15];
  float* out = (float*)d_out;

  char* ws = (char*)d_ws;
  float* agg_raw = (float*)(ws + OFF_AGGRAW);
  float* wv2     = (float*)(ws + OFF_WV2);
  float* c2      = (float*)(ws + OFF_C2);
  float* s_src   = (float*)(ws + OFF_SSRC);
  float* s_dst   = (float*)(ws + OFF_SDST);
  float* wvec    = (float*)(ws + OFF_WVEC);
  int*   sel_map = (int*)(ws + OFF_SELMAP);
  int*   nodelst = (int*)(ws + OFF_NODELST);
  int*   cnt     = (int*)(ws + OFF_CNT);
  int*   deg     = (int*)(ws + OFF_DEG);
  int*   offs    = (int*)(ws + OFF_OFFS);
  int*   cursor  = (int*)(ws + OFF_CURSOR);
  int*   esort   = (int*)(ws + OFF_ESORT);
  unsigned short* aggxh = (unsigned short*)(ws + OFF_AGGXH);
  unsigned short* aggxl = (unsigned short*)(ws + OFF_AGGXL);
  unsigned short* xsh   = (unsigned short*)(ws + OFF_XSH);
  unsigned short* xsl   = (unsigned short*)(ws + OFF_XSL);
  unsigned short* hh    = (unsigned short*)(ws + OFF_HH);
  unsigned short* hl    = (unsigned short*)(ws + OFF_HL);
  float* cbuf    = (float*)(ws + OFF_CBUF);
  float* l2out   = (float*)(ws + OFF_L2OUT);
  unsigned short* whi = (unsigned short*)(ws + OFF_WHI);
  unsigned short* wlo = (unsigned short*)(ws + OFF_WLO);

  // needed-row scratch carved from the aggx region: consumed by score_pass,
  // which runs strictly before gemm_unified writes aggxh/aggxl over it.
  int* need_flag = (int*)(ws + OFF_AGGXH);            // [N]
  int* need_list = need_flag + N;                     // [N]
  int* need_cnt  = cnt + 1;                           // zeroed by init_ws

  init_ws<<<2048, 256, 0, stream>>>(sel_map, deg, cursor, cnt, cbuf, hh, hl, need_flag);
  prep_kernel<<<6 + (WTOT + 255) / 256, 256, 0, stream>>>(
      gat_W, gat_asrc, gat_adst, wvec, lin1_W, lstm_Wih, lstm_Whh, lin2_W, whi, wlo);
  prep2_kernel<<<6, 256, 0, stream>>>(lin1_W, lin1_b, wvec, wv2, c2);
  roots_assign<<<(NB + 255) / 256, 256, 0, stream>>>(root_idx, aggp, sel_map, nodelst, cnt,
                                                     need_flag);

  // edge CSR (needed-row set completed here)
  const int egrid = (E + 256 * EPT - 1) / (256 * EPT);
  count_edges<<<egrid, 256, 0, stream>>>(edge_idx, sel_map, deg);
  scan_kernel<<<1, 1024, 0, stream>>>(deg, offs);
  scatter_edges2<<<egrid, 256, 0, stream>>>(edge_idx, sel_map, offs, cursor, esort,
                                            need_flag);
  compact_need<<<(N + 255) / 256, 256, 0, stream>>>(need_flag, need_list, need_cnt);

  // scores over needed rows (pure gather+dot; no lin1 GEMM over sources)
  score_pass<<<(N + 15) / 16, 256, 0, stream>>>(
      node_feat, send_embd, wv2, c2, s_src, s_dst, need_list, need_cnt);

  // raw-feature softmax aggregation per selected destination
  gat_node_kernel<<<NB, 256, 0, stream>>>(nodelst, cnt, offs, esort,
                                          node_feat, send_embd, s_src, s_dst, agg_raw);

  // one lin1 GEMM over 12288 agg rows + 4096 root rows
  gemm_unified<<<256, 256, 0, stream>>>(
      agg_raw, node_feat, send_embd, nodelst, cnt, offs,
      whi + WOFF_L1, wlo + WOFF_L1, lin1_b,
      aggxh, aggxl, xsh, xsl);

  for (int i = 0; i < HOPS; i++) {
    const unsigned short* x1h = (i == 0) ? xsh : hh;
    const unsigned short* x1l = (i == 0) ? xsl : hl;
    hop_fused<<<NB / 16, 256, 0, stream>>>(
        aggxh + (size_t)i * NB * H, aggxl + (size_t)i * NB * H,
        whi + WOFF_GAT + i * 16384, wlo + WOFF_GAT + i * 16384,
        gat_b + (size_t)i * H,
        x1h, x1l,
        whi + WOFF_CAT + i * 196608, wlo + WOFF_CAT + i * 196608,
        lstm_b + (size_t)i * 512,
        cbuf, hh, hl,
        whi + WOFF_L2, wlo + WOFF_L2, lin2_b, l2out,
        (i == HOPS - 1) ? 1 : 0);
  }

  scatter_out<<<(NB * H + 255) / 256, 256, 0, stream>>>(l2out, sel_map, root_idx, aggp, out);
}

// Round 7
// 323.758 us; speedup vs baseline: 1.1956x; 1.1956x over previous
//
#include <hip/hip_runtime.h>

// Problem constants (match reference)
constexpr int N  = 100000;   // nodes
constexpr int E  = 1600000;  // edges
constexpr int H  = 128;      // hidden
constexpr int NB = 4096;     // root pairs
constexpr int HOPS = 3;
constexpr int EPT = 8;       // edges per thread in E-scans (MLP)

// Swizzled converted-weight buffer (element offsets into whi/wlo ushort arrays).
constexpr int WOFF_L1  = 0;                      // numC=8,  numT=8  (K=256)
constexpr int WOFF_GAT = 32768;                  // 3 x numC=8,  numT=4
constexpr int WOFF_CAT = 81920;                  // 3 x numC=32, numT=12 (gate-perm)
constexpr int WOFF_L2  = 671744;                 // numC=8,  numT=4
constexpr int WTOT     = 688128;

// ---------------- workspace layout (byte offsets, 256B aligned) ---------------
constexpr size_t ALIGN = 256;
constexpr size_t alup(size_t x) { return (x + ALIGN - 1) & ~(ALIGN - 1); }

constexpr size_t OFF_X       = 0;                                        // repurposed (below)
constexpr size_t OFF_SSRC    = alup(OFF_X + (size_t)N * H * 4);          // [3][N] f32
constexpr size_t OFF_SDST    = alup(OFF_SSRC + (size_t)3 * N * 4);       // [3][N] f32
constexpr size_t OFF_WVEC    = alup(OFF_SDST + (size_t)3 * N * 4);       // [6][128] f32
constexpr size_t OFF_SELMAP  = alup(OFF_WVEC + 6 * H * 4);               // [N] int
constexpr size_t OFF_NODELST = alup(OFF_SELMAP + (size_t)N * 4);         // [4096] int
constexpr size_t OFF_CNT     = alup(OFF_NODELST + NB * 4);               // [64] int
constexpr size_t OFF_DEG     = alup(OFF_CNT + 256);                      // [4096] int
constexpr size_t OFF_OFFS    = alup(OFF_DEG + NB * 4);                   // [4097] int
constexpr size_t OFF_CURSOR  = alup(OFF_OFFS + (NB + 1) * 4);            // [4096] int
constexpr size_t OFF_ESORT   = alup(OFF_CURSOR + NB * 4);                // [E] int
constexpr size_t OFF_AGGXH   = alup(OFF_ESORT + (size_t)E * 4);          // [3][4096][128] us
constexpr size_t OFF_AGGXL   = alup(OFF_AGGXH + (size_t)3 * NB * H * 2);
constexpr size_t OFF_XSH     = alup(OFF_AGGXL + (size_t)3 * NB * H * 2); // [4096][128] us
constexpr size_t OFF_XSL     = alup(OFF_XSH + (size_t)NB * H * 2);
constexpr size_t OFF_L2OUT   = alup(OFF_XSL + (size_t)NB * H * 2);       // [4096][128] f32
constexpr size_t OFF_WHI     = alup(OFF_L2OUT + (size_t)NB * H * 4);     // [WTOT] us
constexpr size_t OFF_WLO     = alup(OFF_WHI + (size_t)WTOT * 2);         // [WTOT] us

// Repurposed old-x region (51.2 MB): raw-feature aggregation + folded score vecs
constexpr size_t OFF_AGGRAW  = OFF_X;                                    // [3*4096][256] f32 (12.6MB)
constexpr size_t OFF_WV2     = OFF_X + (size_t)16 * 1024 * 1024;         // [6][256] f32
constexpr size_t OFF_C2      = OFF_WV2 + 6 * 256 * 4;                    // [6] f32

__device__ __forceinline__ float lrelu(float v) { return v > 0.f ? v : 0.2f * v; }
__device__ __forceinline__ float sigmoidf_(float v) { return 1.f / (1.f + __expf(-v)); }

__device__ __forceinline__ unsigned short f2bf(float f) {
  unsigned u = __float_as_uint(f);
  unsigned r = (u + 0x7FFFu + ((u >> 16) & 1u)) >> 16;
  return (unsigned short)r;
}
__device__ __forceinline__ float bf2f(unsigned short h) {
  return __uint_as_float((unsigned)h << 16);
}
__device__ __forceinline__ void split_rne(float f, unsigned short& hi, unsigned short& lo) {
  unsigned short hh = f2bf(f);
  hi = hh;
  lo = f2bf(f - bf2f(hh));
}
// 4-op truncation split (GEMM hot path); pointer outs (vector elems can't bind refs)
__device__ __forceinline__ void split_trunc(float f, short* hi, short* lo) {
  unsigned u = __float_as_uint(f);
  *hi = (short)(u >> 16);
  float r = f - __uint_as_float(u & 0xFFFF0000u);
  *lo = (short)(__float_as_uint(r) >> 16);
}

typedef short bf16x8 __attribute__((ext_vector_type(8)));
typedef float f32x4  __attribute__((ext_vector_type(4)));

#define MFMA3(ACC, AH, AL, BH, BL)                                               \
  ACC = __builtin_amdgcn_mfma_f32_16x16x32_bf16(AH, BH, ACC, 0, 0, 0);           \
  ACC = __builtin_amdgcn_mfma_f32_16x16x32_bf16(AH, BL, ACC, 0, 0, 0);           \
  ACC = __builtin_amdgcn_mfma_f32_16x16x32_bf16(AL, BH, ACC, 0, 0, 0);

// ---------------- init: replaces memsets ---------------------------------------
// (h/c state now lives in the fused hop kernel: no hh/hl/cbuf zeroing needed)
__global__ void init_ws(int* __restrict__ sel_map, int* __restrict__ deg,
                        int* __restrict__ cursor, int* __restrict__ cnt,
                        int* __restrict__ need_flag) {
  int i = blockIdx.x * 256 + threadIdx.x;
  int stride = gridDim.x * 256;
  for (int n = i; n < N; n += stride) { sel_map[n] = -1; need_flag[n] = 0; }
  for (int n = i; n < NB; n += stride) { deg[n] = 0; cursor[n] = 0; }
  if (i < 64) cnt[i] = 0;
}

// ---------------- prep: wvec + weight convert to swizzled fragment tiles -------
__global__ void prep_kernel(const float* __restrict__ gat_W,
                            const float* __restrict__ a_src,
                            const float* __restrict__ a_dst,
                            float* __restrict__ wvec,
                            const float* __restrict__ lin1_W,
                            const float* __restrict__ Wih,
                            const float* __restrict__ Whh,
                            const float* __restrict__ lin2_W,
                            unsigned short* __restrict__ whi,
                            unsigned short* __restrict__ wlo) {
  if (blockIdx.x < 6) {
    int i = blockIdx.x >> 1, which = blockIdx.x & 1;
    int k = threadIdx.x;
    __shared__ float av[H];
    if (k < H) av[k] = which ? a_dst[i * H + k] : a_src[i * H + k];
    __syncthreads();
    if (k >= H) return;
    const float* Wr = gat_W + (size_t)i * H * H + (size_t)k * H;
    float s = 0.f;
    #pragma unroll 8
    for (int j = 0; j < H; j++) s = fmaf(Wr[j], av[j], s);
    wvec[(i * 2 + which) * H + k] = s;
    return;
  }
  int idx = (blockIdx.x - 6) * 256 + threadIdx.x;
  if (idx >= WTOT) return;
  float v;
  if (idx < WOFF_GAT) {                      // lin1: numC=8, K=256
    int rel = idx;
    int e = rel & 7, lane = (rel >> 3) & 63, tile = rel >> 9;
    int nl = lane & 15, quad = lane >> 4;
    int c = tile & 7, t = tile >> 3;
    int n = c * 16 + nl, k = t * 32 + quad * 8 + e;
    v = lin1_W[k * 128 + n];
  } else if (idx < WOFF_CAT) {               // gat: 3 x numC=8, K=128
    int rel = idx - WOFF_GAT;
    int hop = rel / 16384; rel %= 16384;
    int e = rel & 7, lane = (rel >> 3) & 63, tile = rel >> 9;
    int nl = lane & 15, quad = lane >> 4;
    int c = tile & 7, t = tile >> 3;
    int n = c * 16 + nl, k = t * 32 + quad * 8 + e;
    v = gat_W[hop * 16384 + k * 128 + n];
  } else if (idx < WOFF_L2) {                // CAT: 3 x numC=32, K=384, gate-perm
    int rel = idx - WOFF_CAT;
    int hop = rel / 196608; rel %= 196608;
    int e = rel & 7, lane = (rel >> 3) & 63, tile = rel >> 9;
    int nl = lane & 15, quad = lane >> 4;
    int c = tile & 31, t = tile >> 5;
    int ftile = c >> 2, g = c & 3;           // virtual col tile -> (feature-tile, gate)
    int col = g * 128 + ftile * 16 + nl;     // original column in [Wih;Whh]
    int k = t * 32 + quad * 8 + e;
    v = (k < 256) ? Wih[hop * 131072 + k * 512 + col]
                  : Whh[hop * 65536 + (k - 256) * 512 + col];
  } else {                                   // lin2: numC=8, K=128
    int rel = idx - WOFF_L2;
    int e = rel & 7, lane = (rel >> 3) & 63, tile = rel >> 9;
    int nl = lane & 15, quad = lane >> 4;
    int c = tile & 7, t = tile >> 3;
    int n = c * 16 + nl, k = t * 32 + quad * 8 + e;
    v = lin2_W[k * 128 + n];
  }
  unsigned short hh, ll;
  split_rne(v, hh, ll);
  whi[idx] = hh;
  wlo[idx] = ll;
}

// ---------------- prep2: fold lin1 into score vectors --------------------------
__global__ void prep2_kernel(const float* __restrict__ lin1_W,
                             const float* __restrict__ lin1_b,
                             const float* __restrict__ wvec,
                             float* __restrict__ wv2, float* __restrict__ c2) {
  int v = blockIdx.x;          // 0..5
  int j = threadIdx.x;         // 0..255 (row of W1)
  __shared__ float wv[H];
  if (j < H) wv[j] = wvec[v * H + j];
  __syncthreads();
  const float* Wr = lin1_W + (size_t)j * H;
  float s = 0.f;
  #pragma unroll 8
  for (int m = 0; m < H; m++) s = fmaf(Wr[m], wv[m], s);
  wv2[v * 256 + j] = s;
  if (j == 0) {
    float cc = 0.f;
    for (int m = 0; m < H; m++) cc = fmaf(lin1_b[m], wv[m], cc);
    c2[v] = cc;
  }
}

// ---------------- roots: mark + compact-id assign ------------------------------
__global__ void roots_assign(const int* __restrict__ root, const int* __restrict__ aggp,
                             int* __restrict__ sel_map, int* __restrict__ node_list,
                             int* __restrict__ cnt, int* __restrict__ need_flag) {
  int b = blockIdx.x * 256 + threadIdx.x;
  if (b >= NB) return;
  int node = root[2 * b + (aggp[0] ? 0 : 1)];
  need_flag[node] = 1;                       // plain store, idempotent
  int old = atomicCAS(&sel_map[node], -1, -2);
  if (old == -1) {
    int c = atomicAdd(cnt, 1);
    sel_map[node] = c;
    node_list[c] = node;
  }
}

// ---------------- edge CSR by destination: EPT-batched for MLP -----------------
__global__ void count_edges(const int* __restrict__ ei, const int* __restrict__ sel_map,
                            int* __restrict__ deg) {
  const int T = gridDim.x * 256;
  const int base = blockIdx.x * 256 + threadIdx.x;
  int dn[EPT];
  #pragma unroll
  for (int k = 0; k < EPT; k++) {
    int e = base + k * T;
    dn[k] = (e < E) ? ei[E + e] : -1;
  }
  #pragma unroll
  for (int k = 0; k < EPT; k++) {
    if (dn[k] >= 0) dn[k] = sel_map[dn[k]];
  }
  #pragma unroll
  for (int k = 0; k < EPT; k++) {
    if (dn[k] >= 0) atomicAdd(&deg[dn[k]], 1);
  }
}

__global__ __launch_bounds__(1024)
void scan_kernel(const int* __restrict__ deg, int* __restrict__ offs) {
  __shared__ int part[1024];
  int t = threadIdx.x;
  int base = t * 4;
  int v0 = deg[base], v1 = deg[base + 1], v2 = deg[base + 2], v3 = deg[base + 3];
  int s = v0 + v1 + v2 + v3;
  part[t] = s;
  __syncthreads();
  for (int off = 1; off < 1024; off <<= 1) {
    int tmp = (t >= off) ? part[t - off] : 0;
    __syncthreads();
    part[t] += tmp;
    __syncthreads();
  }
  int run = part[t] - s;
  offs[base] = run; run += v0;
  offs[base + 1] = run; run += v1;
  offs[base + 2] = run; run += v2;
  offs[base + 3] = run;
  if (t == 1023) offs[NB] = part[1023];
}

__global__ void scatter_edges2(const int* __restrict__ ei, const int* __restrict__ sel_map,
                               const int* __restrict__ offs, int* __restrict__ cursor,
                               int* __restrict__ es_sorted, int* __restrict__ need_flag) {
  const int T = gridDim.x * 256;
  const int base = blockIdx.x * 256 + threadIdx.x;
  int dn[EPT], sn[EPT];
  #pragma unroll
  for (int k = 0; k < EPT; k++) {
    int e = base + k * T;
    dn[k] = (e < E) ? ei[E + e] : -1;
  }
  #pragma unroll
  for (int k = 0; k < EPT; k++) {
    if (dn[k] >= 0) dn[k] = sel_map[dn[k]];
  }
  #pragma unroll
  for (int k = 0; k < EPT; k++) {
    int e = base + k * T;
    if (dn[k] >= 0) sn[k] = ei[e];
  }
  #pragma unroll
  for (int k = 0; k < EPT; k++) {
    if (dn[k] >= 0) {
      int p = atomicAdd(&cursor[dn[k]], 1);
      es_sorted[offs[dn[k]] + p] = sn[k];
      need_flag[sn[k]] = 1;                  // plain store, idempotent (no RMW)
    }
  }
}

// ---------------- needed-set compaction (wave-ballot, ~1.5K atomics total) -----
__global__ void compact_need(const int* __restrict__ need_flag,
                             int* __restrict__ need_list, int* __restrict__ need_cnt) {
  int i = blockIdx.x * 256 + threadIdx.x;
  bool f = (i < N) && (need_flag[i] != 0);
  unsigned long long mask = __ballot(f);
  int lane = threadIdx.x & 63;
  int wcnt = __popcll(mask);
  int base = 0;
  if (lane == 0 && wcnt > 0) base = atomicAdd(need_cnt, wcnt);
  base = __shfl(base, 0);
  if (f) {
    int prefix = __popcll(mask & ((1ull << lane) - 1ull));
    need_list[base + prefix] = i;
  }
}

// ---------------- score pass: s = cat . wv2 + c2 over needed rows --------------
__global__ __launch_bounds__(256)
void score_pass(const float* __restrict__ a0, const float* __restrict__ a1,
                const float* __restrict__ wv2, const float* __restrict__ c2,
                float* __restrict__ s_src, float* __restrict__ s_dst,
                const int* __restrict__ need_list, const int* __restrict__ need_cnt) {
  const int nneed = need_cnt[0];
  if (blockIdx.x * 16 >= nneed) return;
  __shared__ float Ws[6 * 256];
  __shared__ float C2s[6];
  const int t = threadIdx.x, lane = t & 63, wave = t >> 6;
  const int nl = lane & 15;
  #pragma unroll
  for (int v = 0; v < 6; v++) Ws[v * 256 + t] = wv2[v * 256 + t];
  if (t < 6) C2s[t] = c2[t];
  __syncthreads();

  int r = blockIdx.x * 16 + wave * 4 + (lane >> 4);
  int row = (r < nneed) ? need_list[r] : -1;
  int rc = (row < 0) ? 0 : row;
  const float* src = (nl < 8) ? (a0 + (size_t)rc * H + nl * 16)
                              : (a1 + (size_t)rc * H + (nl - 8) * 16);
  float4 va[4];
  #pragma unroll
  for (int q = 0; q < 4; q++) va[q] = ((const float4*)src)[q];

  float p[6] = {0.f, 0.f, 0.f, 0.f, 0.f, 0.f};
  #pragma unroll
  for (int q = 0; q < 4; q++) {
    float4 v4 = va[q];
    #pragma unroll
    for (int v = 0; v < 6; v++) {
      float4 w4 = *(const float4*)&Ws[v * 256 + nl * 16 + q * 4];
      p[v] = fmaf(v4.x, w4.x, p[v]);
      p[v] = fmaf(v4.y, w4.y, p[v]);
      p[v] = fmaf(v4.z, w4.z, p[v]);
      p[v] = fmaf(v4.w, w4.w, p[v]);
    }
  }
  #pragma unroll
  for (int m = 1; m < 16; m <<= 1)
    #pragma unroll
    for (int v = 0; v < 6; v++) p[v] += __shfl_xor(p[v], m);
  if (nl == 0 && row >= 0) {
    #pragma unroll
    for (int h3 = 0; h3 < 3; h3++) {
      s_src[h3 * N + row] = p[2 * h3 + 0] + C2s[2 * h3 + 0];
      s_dst[h3 * N + row] = p[2 * h3 + 1] + C2s[2 * h3 + 1];
    }
  }
}

// ---------------- per-destination GAT softmax aggregation (RAW features) -------
__global__ __launch_bounds__(256)
void gat_node_kernel(const int* __restrict__ node_list, const int* __restrict__ cntp,
                     const int* __restrict__ offs, const int* __restrict__ es_sorted,
                     const float* __restrict__ a0, const float* __restrict__ a1,
                     const float* __restrict__ s_src, const float* __restrict__ s_dst,
                     float* __restrict__ agg_raw) {
  int c = blockIdx.x;
  if (c >= cntp[0]) return;
  int t = threadIdx.x;
  int n = node_list[c];
  float sd0 = s_dst[0 * N + n], sd1 = s_dst[1 * N + n], sd2 = s_dst[2 * N + n];
  int e0 = offs[c], e1 = offs[c + 1];
  float m0 = -1e30f, m1 = -1e30f, m2 = -1e30f;
  for (int e = e0 + t; e < e1; e += 256) {
    int s = es_sorted[e];
    m0 = fmaxf(m0, lrelu(s_src[0 * N + s] + sd0));
    m1 = fmaxf(m1, lrelu(s_src[1 * N + s] + sd1));
    m2 = fmaxf(m2, lrelu(s_src[2 * N + s] + sd2));
  }
  __shared__ float red[3][256];
  red[0][t] = m0; red[1][t] = m1; red[2][t] = m2;
  __syncthreads();
  for (int s2 = 128; s2 > 0; s2 >>= 1) {
    if (t < s2) {
      red[0][t] = fmaxf(red[0][t], red[0][t + s2]);
      red[1][t] = fmaxf(red[1][t], red[1][t + s2]);
      red[2][t] = fmaxf(red[2][t], red[2][t + s2]);
    }
    __syncthreads();
  }
  m0 = red[0][0]; m1 = red[1][0]; m2 = red[2][0];
  float u0 = 0.f, u1 = 0.f, u2 = 0.f, z0 = 0.f, z1 = 0.f, z2 = 0.f;
  for (int e = e0; e < e1; e++) {
    int s = es_sorted[e];
    float xs = (t < 128) ? a0[(size_t)s * H + t] : a1[(size_t)s * H + (t - 128)];
    float ex0 = __expf(lrelu(s_src[0 * N + s] + sd0) - m0);
    float ex1 = __expf(lrelu(s_src[1 * N + s] + sd1) - m1);
    float ex2 = __expf(lrelu(s_src[2 * N + s] + sd2) - m2);
    z0 += ex0; z1 += ex1; z2 += ex2;
    u0 = fmaf(ex0, xs, u0); u1 = fmaf(ex1, xs, u1); u2 = fmaf(ex2, xs, u2);
  }
  size_t cb = (size_t)c * 256 + t;
  bool any = e1 > e0;
  agg_raw[0 * ((size_t)NB * 256) + cb] = any ? u0 / z0 : 0.f;
  agg_raw[1 * ((size_t)NB * 256) + cb] = any ? u1 / z1 : 0.f;
  agg_raw[2 * ((size_t)NB * 256) + cb] = any ? u2 / z2 : 0.f;
}

// ---------------- unified lin1 GEMM: 12288 agg rows + 4096 root rows -----------
__global__ __launch_bounds__(256)
void gemm_unified(const float* __restrict__ agg_raw,
                  const float* __restrict__ a0, const float* __restrict__ a1,
                  const int* __restrict__ node_list, const int* __restrict__ cntp,
                  const int* __restrict__ offs,
                  const unsigned short* __restrict__ Bth,
                  const unsigned short* __restrict__ Btl,
                  const float* __restrict__ bias,
                  unsigned short* __restrict__ aggxh, unsigned short* __restrict__ aggxl,
                  unsigned short* __restrict__ xsh, unsigned short* __restrict__ xsl) {
  const int t = threadIdx.x, lane = t & 63, wave = t >> 6;
  const int nl = lane & 15, quad = lane >> 4;
  const int rt = blockIdx.x * 64 + wave * 16;
  const int cnt = cntp[0];

  int gr = rt + nl;
  const float *pA, *pB;
  if (gr < 12288) {
    pA = agg_raw + (size_t)gr * 256;
    pB = pA + 128;
  } else {
    int cc = gr - 12288;
    int node = (cc < cnt) ? node_list[cc] : 0;
    pA = a0 + (size_t)node * H;
    pB = a1 + (size_t)node * H;
  }

  f32x4 acc[8];
  #pragma unroll
  for (int c = 0; c < 8; c++) acc[c] = (f32x4){0.f, 0.f, 0.f, 0.f};

  #pragma unroll
  for (int kt = 0; kt < 8; kt++) {
    const float* p = ((kt < 4) ? pA : pB) + (kt & 3) * 32 + quad * 8;
    bf16x8 ahi, alo;
    {
      float4 v0 = *(const float4*)p;
      float4 v1 = *(const float4*)(p + 4);
      float af[8] = {v0.x, v0.y, v0.z, v0.w, v1.x, v1.y, v1.z, v1.w};
      #pragma unroll
      for (int j = 0; j < 8; j++) {
        short h_, l_;
        split_trunc(af[j], &h_, &l_);
        ahi[j] = h_;
        alo[j] = l_;
      }
    }
    #pragma unroll
    for (int c = 0; c < 8; c++) {
      size_t boff = ((size_t)(kt * 8 + c) * 64 + lane) * 8;   // coalesced frag tile
      bf16x8 bh = *(const bf16x8*)(Bth + boff);
      bf16x8 bl = *(const bf16x8*)(Btl + boff);
      MFMA3(acc[c], ahi, alo, bh, bl);
    }
  }

  float bv[8];
  #pragma unroll
  for (int c = 0; c < 8; c++) bv[c] = bias[c * 16 + nl];

  #pragma unroll
  for (int r = 0; r < 4; r++) {
    int g2 = rt + quad * 4 + r;
    if (g2 < 12288) {
      int cc = g2 & 4095, h = g2 >> 12;
      bool he = offs[cc + 1] > offs[cc];
      size_t base = (size_t)h * NB * H + (size_t)cc * H;
      #pragma unroll
      for (int c = 0; c < 8; c++) {
        float val = acc[c][r] + (he ? bv[c] : 0.f);
        unsigned short vh, vl;
        split_rne(val, vh, vl);
        aggxh[base + c * 16 + nl] = vh;
        aggxl[base + c * 16 + nl] = vl;
      }
    } else {
      int cc = g2 - 12288;
      size_t base = (size_t)cc * H;
      #pragma unroll
      for (int c = 0; c < 8; c++) {
        float val = acc[c][r] + bv[c];
        unsigned short vh, vl;
        split_rne(val, vh, vl);
        xsh[base + c * 16 + nl] = vh;
        xsl[base + c * 16 + nl] = vl;
      }
    }
  }
}

// ---------------- fused 3-hop depth kernel -------------------------------------
// GeniePathLazy: all aggx are precomputed from x, and the LSTM recurrence is
// per-ROW local -> all 3 hops fuse into one kernel with h in LDS, c in regs.
// Round-6 counters: hop_fused was 3 x 40us at 1 wave/SIMD (occupancy 9.5%),
// pure latency. This kernel: 512 threads (8 waves = 2/SIMD), no hh/hl/cbuf
// global round-trips, no inter-launch bubbles, hop0 skips h@Whh exactly (h=0).
// Wave w owns feature-tile w (16 features x all 4 gates -> LSTM stays in-lane).
__global__ __launch_bounds__(512)
void hops3_fused(const unsigned short* __restrict__ aggxh,
                 const unsigned short* __restrict__ aggxl,
                 const unsigned short* __restrict__ xsh,
                 const unsigned short* __restrict__ xsl,
                 const unsigned short* __restrict__ gWh_all,
                 const unsigned short* __restrict__ gWl_all,
                 const float* __restrict__ gbias_all,
                 const unsigned short* __restrict__ CWh_all,
                 const unsigned short* __restrict__ CWl_all,
                 const float* __restrict__ lbias_all,
                 const unsigned short* __restrict__ L2h,
                 const unsigned short* __restrict__ L2l,
                 const float* __restrict__ lin2_b, float* __restrict__ l2out) {
  __shared__ unsigned short Ah[16 * 136], Al[16 * 136];   // aggx staging (per hop)
  __shared__ unsigned short Xh[16 * 136], Xl[16 * 136];   // hop-0 x1 (= root x)
  __shared__ unsigned short Th[16 * 136], Tl[16 * 136];   // htmp
  __shared__ unsigned short Hh[16 * 136], Hl[16 * 136];   // h state
  const int t = threadIdx.x, lane = t & 63, wave = t >> 6;  // wave 0..7
  const int nl = lane & 15, quad = lane >> 4;
  const int r0 = blockIdx.x * 16;

  // stage xs (16 rows x 128) into padded LDS, ushort2 granularity
  for (int i = t; i < 16 * 64; i += 512) {
    int row = i >> 6, c2 = (i & 63) * 2;
    *(ushort2*)&Xh[row * 136 + c2] = *(const ushort2*)&xsh[(size_t)(r0 + row) * H + c2];
    *(ushort2*)&Xl[row * 136 + c2] = *(const ushort2*)&xsl[(size_t)(r0 + row) * H + c2];
  }

  float creg[4] = {0.f, 0.f, 0.f, 0.f};   // c-state: rows quad*4+r, feature w*16+nl
  const int f = wave * 16 + nl;

  f32x4 acc2[4];
  #pragma unroll
  for (int hop = 0; hop < 3; hop++) {
    const unsigned short* agh = aggxh + (size_t)hop * NB * H;
    const unsigned short* agl = aggxl + (size_t)hop * NB * H;
    __syncthreads();   // prev pointwise Hs-writes + prev GEMM1 Ah-reads done
    for (int i = t; i < 16 * 64; i += 512) {
      int row = i >> 6, c2 = (i & 63) * 2;
      *(ushort2*)&Ah[row * 136 + c2] = *(const ushort2*)&agh[(size_t)(r0 + row) * H + c2];
      *(ushort2*)&Al[row * 136 + c2] = *(const ushort2*)&agl[(size_t)(r0 + row) * H + c2];
    }
    __syncthreads();

    // ---- GEMM1: htmp = tanh(aggx @ gatW + gb); wave w -> col-tile w
    const unsigned short* gWh = gWh_all + hop * 16384;
    const unsigned short* gWl = gWl_all + hop * 16384;
    f32x4 acc1 = (f32x4){0.f, 0.f, 0.f, 0.f};
    #pragma unroll
    for (int kt = 0; kt < 4; kt++) {
      int kk = kt * 32 + quad * 8;
      bf16x8 ah = *(const bf16x8*)&Ah[nl * 136 + kk];
      bf16x8 al = *(const bf16x8*)&Al[nl * 136 + kk];
      size_t boff = ((size_t)(kt * 8 + wave) * 64 + lane) * 8;
      bf16x8 bh = *(const bf16x8*)(gWh + boff);
      bf16x8 bl = *(const bf16x8*)(gWl + boff);
      MFMA3(acc1, ah, al, bh, bl);
    }
    {
      float bv = gbias_all[hop * H + f];
      #pragma unroll
      for (int r = 0; r < 4; r++) {
        int rl = quad * 4 + r;
        float v = tanhf(acc1[r] + bv);
        unsigned short vh, vl2;
        split_rne(v, vh, vl2);
        Th[rl * 136 + f] = vh;
        Tl[rl * 136 + f] = vl2;
      }
    }
    __syncthreads();

    // ---- GEMM2: gates[16x(4x128)] = [htmp|x1|h] @ CAT; wave w -> gates of ftile w
    const unsigned short* CWh = CWh_all + hop * 196608;
    const unsigned short* CWl = CWl_all + hop * 196608;
    #pragma unroll
    for (int g = 0; g < 4; g++) acc2[g] = (f32x4){0.f, 0.f, 0.f, 0.f};
    #pragma unroll
    for (int kt = 0; kt < 4; kt++) {          // K rows 0..127: htmp
      int kk = kt * 32 + quad * 8;
      bf16x8 ah = *(const bf16x8*)&Th[nl * 136 + kk];
      bf16x8 al = *(const bf16x8*)&Tl[nl * 136 + kk];
      #pragma unroll
      for (int g = 0; g < 4; g++) {
        size_t boff = ((size_t)(kt * 32 + wave * 4 + g) * 64 + lane) * 8;
        bf16x8 bh = *(const bf16x8*)(CWh + boff);
        bf16x8 bl = *(const bf16x8*)(CWl + boff);
        MFMA3(acc2[g], ah, al, bh, bl);
      }
    }
    #pragma unroll
    for (int kt = 0; kt < 4; kt++) {          // K rows 128..255 (x1) and 256..383 (h)
      int kk = kt * 32 + quad * 8;
      bf16x8 ah, al;
      if (hop == 0) {                         // x1 = root x; h = 0 (skip exactly)
        ah = *(const bf16x8*)&Xh[nl * 136 + kk];
        al = *(const bf16x8*)&Xl[nl * 136 + kk];
      } else {                                // x1 = h_prev = h (same fragment)
        ah = *(const bf16x8*)&Hh[nl * 136 + kk];
        al = *(const bf16x8*)&Hl[nl * 136 + kk];
      }
      #pragma unroll
      for (int g = 0; g < 4; g++) {
        size_t boff = ((size_t)((kt + 4) * 32 + wave * 4 + g) * 64 + lane) * 8;
        bf16x8 bh = *(const bf16x8*)(CWh + boff);
        bf16x8 bl = *(const bf16x8*)(CWl + boff);
        MFMA3(acc2[g], ah, al, bh, bl);
      }
      if (hop > 0) {
        #pragma unroll
        for (int g = 0; g < 4; g++) {
          size_t boff = ((size_t)((kt + 8) * 32 + wave * 4 + g) * 64 + lane) * 8;
          bf16x8 bh = *(const bf16x8*)(CWh + boff);
          bf16x8 bl = *(const bf16x8*)(CWl + boff);
          MFMA3(acc2[g], ah, al, bh, bl);
        }
      }
    }
    __syncthreads();   // Hs reads (GEMM2) done before pointwise rewrites Hs

    // ---- LSTM pointwise; lane has all 4 gates of feature f
    {
      const float* lb = lbias_all + hop * 512;
      float b_i = lb[0 * 128 + f], b_f = lb[1 * 128 + f];
      float b_g = lb[2 * 128 + f], b_o = lb[3 * 128 + f];
      #pragma unroll
      for (int r = 0; r < 4; r++) {
        int rl = quad * 4 + r;
        float gi = acc2[0][r] + b_i;
        float gf = acc2[1][r] + b_f;
        float gg = acc2[2][r] + b_g;
        float go = acc2[3][r] + b_o;
        float cn = sigmoidf_(gf) * creg[r] + sigmoidf_(gi) * tanhf(gg);
        float hn = sigmoidf_(go) * tanhf(cn);
        creg[r] = cn;
        unsigned short vh, vl2;
        split_rne(hn, vh, vl2);
        Hh[rl * 136 + f] = vh;
        Hl[rl * 136 + f] = vl2;
      }
    }
  }
  __syncthreads();

  // ---- GEMM3: lin2 on final h; wave w -> col-tile w
  f32x4 acc3 = (f32x4){0.f, 0.f, 0.f, 0.f};
  #pragma unroll
  for (int kt = 0; kt < 4; kt++) {
    int kk = kt * 32 + quad * 8;
    bf16x8 ah = *(const bf16x8*)&Hh[nl * 136 + kk];
    bf16x8 al = *(const bf16x8*)&Hl[nl * 136 + kk];
    size_t boff = ((size_t)(kt * 8 + wave) * 64 + lane) * 8;
    bf16x8 bh = *(const bf16x8*)(L2h + boff);
    bf16x8 bl = *(const bf16x8*)(L2l + boff);
    MFMA3(acc3, ah, al, bh, bl);
  }
  {
    float bv = lin2_b[f];
    #pragma unroll
    for (int r = 0; r < 4; r++) {
      int row = r0 + quad * 4 + r;
      l2out[(size_t)row * H + f] = acc3[r] + bv;
    }
  }
}

// ---------------- output gather ------------------------------------------------
__global__ void scatter_out(const float* __restrict__ l2out, const int* __restrict__ sel_map,
                            const int* __restrict__ root, const int* __restrict__ aggp,
                            float* __restrict__ out) {
  int id = blockIdx.x * 256 + threadIdx.x;
  if (id >= NB * H) return;
  int b = id >> 7, f = id & 127;
  int node = root[2 * b + (aggp[0] ? 0 : 1)];
  int c = sel_map[node];
  out[id] = l2out[(size_t)c * H + f];
}

// ==============================================================================
extern "C" void kernel_launch(void* const* d_in, const int* in_sizes, int n_in,
                              void* d_out, int out_size, void* d_ws, size_t ws_size,
                              hipStream_t stream) {
  const float* node_feat = (const float*)d_in[0];
  const float* send_embd = (const float*)d_in[1];
  const int*   edge_idx  = (const int*)d_in[2];
  const int*   root_idx  = (const int*)d_in[3];
  const int*   aggp      = (const int*)d_in[4];
  const float* lin1_W    = (const float*)d_in[5];
  const float* lin1_b    = (const float*)d_in[6];
  const float* gat_W     = (const float*)d_in[7];
  const float* gat_asrc  = (const float*)d_in[8];
  const float* gat_adst  = (const float*)d_in[9];
  const float* gat_b     = (const float*)d_in[10];
  const float* lstm_Wih  = (const float*)d_in[11];
  const float* lstm_Whh  = (const float*)d_in[12];
  const float* lstm_b    = (const float*)d_in[13];
  const float* lin2_W    = (const float*)d_in[14];
  const float* lin2_b    = (const float*)d_in[15];
  float* out = (float*)d_out;

  char* ws = (char*)d_ws;
  float* agg_raw = (float*)(ws + OFF_AGGRAW);
  float* wv2     = (float*)(ws + OFF_WV2);
  float* c2      = (float*)(ws + OFF_C2);
  float* s_src   = (float*)(ws + OFF_SSRC);
  float* s_dst   = (float*)(ws + OFF_SDST);
  float* wvec    = (float*)(ws + OFF_WVEC);
  int*   sel_map = (int*)(ws + OFF_SELMAP);
  int*   nodelst = (int*)(ws + OFF_NODELST);
  int*   cnt     = (int*)(ws + OFF_CNT);
  int*   deg     = (int*)(ws + OFF_DEG);
  int*   offs    = (int*)(ws + OFF_OFFS);
  int*   cursor  = (int*)(ws + OFF_CURSOR);
  int*   esort   = (int*)(ws + OFF_ESORT);
  unsigned short* aggxh = (unsigned short*)(ws + OFF_AGGXH);
  unsigned short* aggxl = (unsigned short*)(ws + OFF_AGGXL);
  unsigned short* xsh   = (unsigned short*)(ws + OFF_XSH);
  unsigned short* xsl   = (unsigned short*)(ws + OFF_XSL);
  float* l2out   = (float*)(ws + OFF_L2OUT);
  unsigned short* whi = (unsigned short*)(ws + OFF_WHI);
  unsigned short* wlo = (unsigned short*)(ws + OFF_WLO);

  // needed-row scratch carved from the aggx region: consumed by score_pass,
  // which runs strictly before gemm_unified writes aggxh/aggxl over it.
  int* need_flag = (int*)(ws + OFF_AGGXH);            // [N]
  int* need_list = need_flag + N;                     // [N]
  int* need_cnt  = cnt + 1;                           // zeroed by init_ws

  init_ws<<<512, 256, 0, stream>>>(sel_map, deg, cursor, cnt, need_flag);
  prep_kernel<<<6 + (WTOT + 255) / 256, 256, 0, stream>>>(
      gat_W, gat_asrc, gat_adst, wvec, lin1_W, lstm_Wih, lstm_Whh, lin2_W, whi, wlo);
  prep2_kernel<<<6, 256, 0, stream>>>(lin1_W, lin1_b, wvec, wv2, c2);
  roots_assign<<<(NB + 255) / 256, 256, 0, stream>>>(root_idx, aggp, sel_map, nodelst, cnt,
                                                     need_flag);

  // edge CSR (needed-row set completed here)
  const int egrid = (E + 256 * EPT - 1) / (256 * EPT);
  count_edges<<<egrid, 256, 0, stream>>>(edge_idx, sel_map, deg);
  scan_kernel<<<1, 1024, 0, stream>>>(deg, offs);
  scatter_edges2<<<egrid, 256, 0, stream>>>(edge_idx, sel_map, offs, cursor, esort,
                                            need_flag);
  compact_need<<<(N + 255) / 256, 256, 0, stream>>>(need_flag, need_list, need_cnt);

  // scores over needed rows (pure gather+dot; no lin1 GEMM over sources)
  score_pass<<<(N + 15) / 16, 256, 0, stream>>>(
      node_feat, send_embd, wv2, c2, s_src, s_dst, need_list, need_cnt);

  // raw-feature softmax aggregation per selected destination
  gat_node_kernel<<<NB, 256, 0, stream>>>(nodelst, cnt, offs, esort,
                                          node_feat, send_embd, s_src, s_dst, agg_raw);

  // one lin1 GEMM over 12288 agg rows + 4096 root rows
  gemm_unified<<<256, 256, 0, stream>>>(
      agg_raw, node_feat, send_embd, nodelst, cnt, offs,
      whi + WOFF_L1, wlo + WOFF_L1, lin1_b,
      aggxh, aggxl, xsh, xsl);

  // all 3 hops + lin2, fused (per-row recurrence => no grid sync needed)
  hops3_fused<<<NB / 16, 512, 0, stream>>>(
      aggxh, aggxl, xsh, xsl,
      whi + WOFF_GAT, wlo + WOFF_GAT, gat_b,
      whi + WOFF_CAT, wlo + WOFF_CAT, lstm_b,
      whi + WOFF_L2, wlo + WOFF_L2, lin2_b, l2out);

  scatter_out<<<(NB * H + 255) / 256, 256, 0, stream>>>(l2out, sel_map, root_idx, aggp, out);
}

// Round 8
// 321.539 us; speedup vs baseline: 1.2039x; 1.0069x over previous
//
#include <hip/hip_runtime.h>

// Problem constants (match reference)
constexpr int N  = 100000;   // nodes
constexpr int E  = 1600000;  // edges
constexpr int H  = 128;      // hidden
constexpr int NB = 4096;     // root pairs
constexpr int HOPS = 3;
constexpr int EPT = 8;       // edges per thread in E-scans (MLP)

// Swizzled converted-weight buffer (element offsets into whi/wlo ushort arrays).
constexpr int WOFF_L1  = 0;                      // numC=8,  numT=8  (K=256)
constexpr int WOFF_GAT = 32768;                  // 3 x numC=8,  numT=4
constexpr int WOFF_CAT = 81920;                  // 3 x numC=32, numT=12 (gate-perm)
constexpr int WOFF_L2  = 671744;                 // numC=8,  numT=4
constexpr int WTOT     = 688128;

// ---------------- workspace layout (byte offsets, 256B aligned) ---------------
constexpr size_t ALIGN = 256;
constexpr size_t alup(size_t x) { return (x + ALIGN - 1) & ~(ALIGN - 1); }

constexpr size_t OFF_X       = 0;                                        // repurposed (below)
constexpr size_t OFF_SSRC    = alup(OFF_X + (size_t)N * H * 4);          // [3][N] f32
constexpr size_t OFF_SDST    = alup(OFF_SSRC + (size_t)3 * N * 4);       // [3][N] f32
constexpr size_t OFF_WVEC    = alup(OFF_SDST + (size_t)3 * N * 4);       // [6][128] f32
constexpr size_t OFF_SELMAP  = alup(OFF_WVEC + 6 * H * 4);               // [N] int
constexpr size_t OFF_NODELST = alup(OFF_SELMAP + (size_t)N * 4);         // [4096] int
constexpr size_t OFF_CNT     = alup(OFF_NODELST + NB * 4);               // [64] int
constexpr size_t OFF_DEG     = alup(OFF_CNT + 256);                      // [4096] int
constexpr size_t OFF_OFFS    = alup(OFF_DEG + NB * 4);                   // [4097] int
constexpr size_t OFF_CURSOR  = alup(OFF_OFFS + (NB + 1) * 4);            // [4096] int
constexpr size_t OFF_ESORT   = alup(OFF_CURSOR + NB * 4);                // [E] int
constexpr size_t OFF_AGGXH   = alup(OFF_ESORT + (size_t)E * 4);          // [3][4096][128] us
constexpr size_t OFF_AGGXL   = alup(OFF_AGGXH + (size_t)3 * NB * H * 2);
constexpr size_t OFF_XSH     = alup(OFF_AGGXL + (size_t)3 * NB * H * 2); // [4096][128] us
constexpr size_t OFF_XSL     = alup(OFF_XSH + (size_t)NB * H * 2);
constexpr size_t OFF_L2OUT   = alup(OFF_XSL + (size_t)NB * H * 2);       // [4096][128] f32
constexpr size_t OFF_WHI     = alup(OFF_L2OUT + (size_t)NB * H * 4);     // [WTOT] us
constexpr size_t OFF_WLO     = alup(OFF_WHI + (size_t)WTOT * 2);         // [WTOT] us

// Repurposed old-x region (51.2 MB): raw agg + folded score vecs + pair list
constexpr size_t OFF_AGGRAW  = OFF_X;                                    // [3*4096][256] f32 (12.6MB)
constexpr size_t OFF_WV2     = OFF_X + (size_t)16 * 1024 * 1024;         // [6][256] f32
constexpr size_t OFF_C2     = OFF_WV2 + 6 * 256 * 4;                     // [6] f32
constexpr size_t OFF_PLIST  = OFF_X + (size_t)20 * 1024 * 1024;          // [<=E] int (6.4MB max)

__device__ __forceinline__ float lrelu(float v) { return v > 0.f ? v : 0.2f * v; }
__device__ __forceinline__ float sigmoidf_(float v) { return 1.f / (1.f + __expf(-v)); }

__device__ __forceinline__ unsigned short f2bf(float f) {
  unsigned u = __float_as_uint(f);
  unsigned r = (u + 0x7FFFu + ((u >> 16) & 1u)) >> 16;
  return (unsigned short)r;
}
__device__ __forceinline__ float bf2f(unsigned short h) {
  return __uint_as_float((unsigned)h << 16);
}
__device__ __forceinline__ void split_rne(float f, unsigned short& hi, unsigned short& lo) {
  unsigned short hh = f2bf(f);
  hi = hh;
  lo = f2bf(f - bf2f(hh));
}
// 4-op truncation split (GEMM hot path); pointer outs (vector elems can't bind refs)
__device__ __forceinline__ void split_trunc(float f, short* hi, short* lo) {
  unsigned u = __float_as_uint(f);
  *hi = (short)(u >> 16);
  float r = f - __uint_as_float(u & 0xFFFF0000u);
  *lo = (short)(__float_as_uint(r) >> 16);
}

typedef short bf16x8 __attribute__((ext_vector_type(8)));
typedef float f32x4  __attribute__((ext_vector_type(4)));

#define MFMA3(ACC, AH, AL, BH, BL)                                               \
  ACC = __builtin_amdgcn_mfma_f32_16x16x32_bf16(AH, BH, ACC, 0, 0, 0);           \
  ACC = __builtin_amdgcn_mfma_f32_16x16x32_bf16(AH, BL, ACC, 0, 0, 0);           \
  ACC = __builtin_amdgcn_mfma_f32_16x16x32_bf16(AL, BH, ACC, 0, 0, 0);

// fire-and-forget 16B/lane global->LDS copy (dest = L + lane*16, wave-uniform L)
#define GLOAD_LDS16(G, L)                                                        \
  __builtin_amdgcn_global_load_lds(                                              \
      (const __attribute__((address_space(1))) void*)(G),                        \
      (__attribute__((address_space(3))) void*)(L), 16, 0, 0)

// ---------------- init: replaces memsets ---------------------------------------
__global__ void init_ws(int* __restrict__ sel_map, int* __restrict__ deg,
                        int* __restrict__ cursor, int* __restrict__ cnt,
                        int* __restrict__ need_flag) {
  int i = blockIdx.x * 256 + threadIdx.x;
  int stride = gridDim.x * 256;
  for (int n = i; n < N; n += stride) { sel_map[n] = -1; need_flag[n] = 0; }
  for (int n = i; n < NB; n += stride) { deg[n] = 0; cursor[n] = 0; }
  if (i < 64) cnt[i] = 0;
}

// ---------------- prep: wvec + weight convert to swizzled fragment tiles -------
__global__ void prep_kernel(const float* __restrict__ gat_W,
                            const float* __restrict__ a_src,
                            const float* __restrict__ a_dst,
                            float* __restrict__ wvec,
                            const float* __restrict__ lin1_W,
                            const float* __restrict__ Wih,
                            const float* __restrict__ Whh,
                            const float* __restrict__ lin2_W,
                            unsigned short* __restrict__ whi,
                            unsigned short* __restrict__ wlo) {
  if (blockIdx.x < 6) {
    int i = blockIdx.x >> 1, which = blockIdx.x & 1;
    int k = threadIdx.x;
    __shared__ float av[H];
    if (k < H) av[k] = which ? a_dst[i * H + k] : a_src[i * H + k];
    __syncthreads();
    if (k >= H) return;
    const float* Wr = gat_W + (size_t)i * H * H + (size_t)k * H;
    float s = 0.f;
    #pragma unroll 8
    for (int j = 0; j < H; j++) s = fmaf(Wr[j], av[j], s);
    wvec[(i * 2 + which) * H + k] = s;
    return;
  }
  int idx = (blockIdx.x - 6) * 256 + threadIdx.x;
  if (idx >= WTOT) return;
  float v;
  if (idx < WOFF_GAT) {                      // lin1: numC=8, K=256
    int rel = idx;
    int e = rel & 7, lane = (rel >> 3) & 63, tile = rel >> 9;
    int nl = lane & 15, quad = lane >> 4;
    int c = tile & 7, t = tile >> 3;
    int n = c * 16 + nl, k = t * 32 + quad * 8 + e;
    v = lin1_W[k * 128 + n];
  } else if (idx < WOFF_CAT) {               // gat: 3 x numC=8, K=128
    int rel = idx - WOFF_GAT;
    int hop = rel / 16384; rel %= 16384;
    int e = rel & 7, lane = (rel >> 3) & 63, tile = rel >> 9;
    int nl = lane & 15, quad = lane >> 4;
    int c = tile & 7, t = tile >> 3;
    int n = c * 16 + nl, k = t * 32 + quad * 8 + e;
    v = gat_W[hop * 16384 + k * 128 + n];
  } else if (idx < WOFF_L2) {                // CAT: 3 x numC=32, K=384, gate-perm
    int rel = idx - WOFF_CAT;
    int hop = rel / 196608; rel %= 196608;
    int e = rel & 7, lane = (rel >> 3) & 63, tile = rel >> 9;
    int nl = lane & 15, quad = lane >> 4;
    int c = tile & 31, t = tile >> 5;
    int ftile = c >> 2, g = c & 3;           // virtual col tile -> (feature-tile, gate)
    int col = g * 128 + ftile * 16 + nl;     // original column in [Wih;Whh]
    int k = t * 32 + quad * 8 + e;
    v = (k < 256) ? Wih[hop * 131072 + k * 512 + col]
                  : Whh[hop * 65536 + (k - 256) * 512 + col];
  } else {                                   // lin2: numC=8, K=128
    int rel = idx - WOFF_L2;
    int e = rel & 7, lane = (rel >> 3) & 63, tile = rel >> 9;
    int nl = lane & 15, quad = lane >> 4;
    int c = tile & 7, t = tile >> 3;
    int n = c * 16 + nl, k = t * 32 + quad * 8 + e;
    v = lin2_W[k * 128 + n];
  }
  unsigned short hh, ll;
  split_rne(v, hh, ll);
  whi[idx] = hh;
  wlo[idx] = ll;
}

// ---------------- prep2: fold lin1 into score vectors --------------------------
__global__ void prep2_kernel(const float* __restrict__ lin1_W,
                             const float* __restrict__ lin1_b,
                             const float* __restrict__ wvec,
                             float* __restrict__ wv2, float* __restrict__ c2) {
  int v = blockIdx.x;          // 0..5
  int j = threadIdx.x;         // 0..255 (row of W1)
  __shared__ float wv[H];
  if (j < H) wv[j] = wvec[v * H + j];
  __syncthreads();
  const float* Wr = lin1_W + (size_t)j * H;
  float s = 0.f;
  #pragma unroll 8
  for (int m = 0; m < H; m++) s = fmaf(Wr[m], wv[m], s);
  wv2[v * 256 + j] = s;
  if (j == 0) {
    float cc = 0.f;
    for (int m = 0; m < H; m++) cc = fmaf(lin1_b[m], wv[m], cc);
    c2[v] = cc;
  }
}

// ---------------- roots: mark + compact-id assign ------------------------------
__global__ void roots_assign(const int* __restrict__ root, const int* __restrict__ aggp,
                             int* __restrict__ sel_map, int* __restrict__ node_list,
                             int* __restrict__ cnt, int* __restrict__ need_flag) {
  int b = blockIdx.x * 256 + threadIdx.x;
  if (b >= NB) return;
  int node = root[2 * b + (aggp[0] ? 0 : 1)];
  need_flag[node] = 1;                       // plain store, idempotent
  int old = atomicCAS(&sel_map[node], -1, -2);
  if (old == -1) {
    int c = atomicAdd(cnt, 1);
    sel_map[node] = c;
    node_list[c] = node;
  }
}

// ---------------- edge pass 1: count + pair compaction + need marking ----------
// Single full-E scan (EPT-batched). Selected (d,s) packed: d<4096 (12b) <<17 | s
// (<2^17). One global atomic per BLOCK (~780 total; round-1 showed ~50K
// same-address atomics are catastrophic, ~1.5K invisible). Replaces the old
// count_edges + scatter_edges2 second full-E scan.
__global__ void edge_pass1(const int* __restrict__ ei, const int* __restrict__ sel_map,
                           int* __restrict__ deg, int* __restrict__ plist,
                           int* __restrict__ plist_cnt, int* __restrict__ need_flag) {
  __shared__ int lcnt, lbase;
  const int T = gridDim.x * 256;
  const int tid = threadIdx.x, lane = tid & 63;
  if (tid == 0) lcnt = 0;
  __syncthreads();
  const int base = blockIdx.x * 256 + tid;
  int dn[EPT], sn[EPT], pos[EPT];
  #pragma unroll
  for (int k = 0; k < EPT; k++) {
    int e = base + k * T;
    dn[k] = (e < E) ? ei[E + e] : -1;
  }
  #pragma unroll
  for (int k = 0; k < EPT; k++) {
    if (dn[k] >= 0) dn[k] = sel_map[dn[k]];
  }
  #pragma unroll
  for (int k = 0; k < EPT; k++) {
    int e = base + k * T;
    sn[k] = (dn[k] >= 0) ? ei[e] : 0;
  }
  #pragma unroll
  for (int k = 0; k < EPT; k++) {
    bool f = dn[k] >= 0;
    if (f) { atomicAdd(&deg[dn[k]], 1); need_flag[sn[k]] = 1; }
    unsigned long long mask = __ballot(f);
    int wc = __popcll(mask);
    int wb = 0;
    if (lane == 0 && wc > 0) wb = atomicAdd(&lcnt, wc);   // LDS atomic
    wb = __shfl(wb, 0);
    pos[k] = f ? (wb + __popcll(mask & ((1ull << lane) - 1ull))) : -1;
  }
  __syncthreads();
  if (tid == 0) lbase = (lcnt > 0) ? atomicAdd(plist_cnt, lcnt) : 0;
  __syncthreads();
  #pragma unroll
  for (int k = 0; k < EPT; k++) {
    if (pos[k] >= 0) plist[lbase + pos[k]] = (dn[k] << 17) | sn[k];
  }
}

__global__ __launch_bounds__(1024)
void scan_kernel(const int* __restrict__ deg, int* __restrict__ offs) {
  __shared__ int part[1024];
  int t = threadIdx.x;
  int base = t * 4;
  int v0 = deg[base], v1 = deg[base + 1], v2 = deg[base + 2], v3 = deg[base + 3];
  int s = v0 + v1 + v2 + v3;
  part[t] = s;
  __syncthreads();
  for (int off = 1; off < 1024; off <<= 1) {
    int tmp = (t >= off) ? part[t - off] : 0;
    __syncthreads();
    part[t] += tmp;
    __syncthreads();
  }
  int run = part[t] - s;
  offs[base] = run; run += v0;
  offs[base + 1] = run; run += v1;
  offs[base + 2] = run; run += v2;
  offs[base + 3] = run;
  if (t == 1023) offs[NB] = part[1023];
}

// ---------------- edge pass 2: scatter from compact pair list (~64K) -----------
__global__ void edge_pass2(const int* __restrict__ plist, const int* __restrict__ plist_cnt,
                           const int* __restrict__ offs, int* __restrict__ cursor,
                           int* __restrict__ es_sorted) {
  int np = plist_cnt[0];
  for (int i = blockIdx.x * 256 + threadIdx.x; i < np; i += gridDim.x * 256) {
    int pk = plist[i];
    int d = pk >> 17, s = pk & 0x1FFFF;
    int p = atomicAdd(&cursor[d], 1);
    es_sorted[offs[d] + p] = s;
  }
}

// ---------------- needed-set compaction (wave-ballot, ~1.5K atomics total) -----
__global__ void compact_need(const int* __restrict__ need_flag,
                             int* __restrict__ need_list, int* __restrict__ need_cnt) {
  int i = blockIdx.x * 256 + threadIdx.x;
  bool f = (i < N) && (need_flag[i] != 0);
  unsigned long long mask = __ballot(f);
  int lane = threadIdx.x & 63;
  int wcnt = __popcll(mask);
  int base = 0;
  if (lane == 0 && wcnt > 0) base = atomicAdd(need_cnt, wcnt);
  base = __shfl(base, 0);
  if (f) {
    int prefix = __popcll(mask & ((1ull << lane) - 1ull));
    need_list[base + prefix] = i;
  }
}

// ---------------- score pass: s = cat . wv2 + c2 over needed rows --------------
__global__ __launch_bounds__(256)
void score_pass(const float* __restrict__ a0, const float* __restrict__ a1,
                const float* __restrict__ wv2, const float* __restrict__ c2,
                float* __restrict__ s_src, float* __restrict__ s_dst,
                const int* __restrict__ need_list, const int* __restrict__ need_cnt) {
  const int nneed = need_cnt[0];
  if (blockIdx.x * 16 >= nneed) return;
  __shared__ float Ws[6 * 256];
  __shared__ float C2s[6];
  const int t = threadIdx.x, lane = t & 63, wave = t >> 6;
  const int nl = lane & 15;
  #pragma unroll
  for (int v = 0; v < 6; v++) Ws[v * 256 + t] = wv2[v * 256 + t];
  if (t < 6) C2s[t] = c2[t];
  __syncthreads();

  int r = blockIdx.x * 16 + wave * 4 + (lane >> 4);
  int row = (r < nneed) ? need_list[r] : -1;
  int rc = (row < 0) ? 0 : row;
  const float* src = (nl < 8) ? (a0 + (size_t)rc * H + nl * 16)
                              : (a1 + (size_t)rc * H + (nl - 8) * 16);
  float4 va[4];
  #pragma unroll
  for (int q = 0; q < 4; q++) va[q] = ((const float4*)src)[q];

  float p[6] = {0.f, 0.f, 0.f, 0.f, 0.f, 0.f};
  #pragma unroll
  for (int q = 0; q < 4; q++) {
    float4 v4 = va[q];
    #pragma unroll
    for (int v = 0; v < 6; v++) {
      float4 w4 = *(const float4*)&Ws[v * 256 + nl * 16 + q * 4];
      p[v] = fmaf(v4.x, w4.x, p[v]);
      p[v] = fmaf(v4.y, w4.y, p[v]);
      p[v] = fmaf(v4.z, w4.z, p[v]);
      p[v] = fmaf(v4.w, w4.w, p[v]);
    }
  }
  #pragma unroll
  for (int m = 1; m < 16; m <<= 1)
    #pragma unroll
    for (int v = 0; v < 6; v++) p[v] += __shfl_xor(p[v], m);
  if (nl == 0 && row >= 0) {
    #pragma unroll
    for (int h3 = 0; h3 < 3; h3++) {
      s_src[h3 * N + row] = p[2 * h3 + 0] + C2s[2 * h3 + 0];
      s_dst[h3 * N + row] = p[2 * h3 + 1] + C2s[2 * h3 + 1];
    }
  }
}

// ---------------- per-destination GAT softmax aggregation (RAW features) -------
__global__ __launch_bounds__(256)
void gat_node_kernel(const int* __restrict__ node_list, const int* __restrict__ cntp,
                     const int* __restrict__ offs, const int* __restrict__ es_sorted,
                     const float* __restrict__ a0, const float* __restrict__ a1,
                     const float* __restrict__ s_src, const float* __restrict__ s_dst,
                     float* __restrict__ agg_raw) {
  int c = blockIdx.x;
  if (c >= cntp[0]) return;
  int t = threadIdx.x;
  int n = node_list[c];
  float sd0 = s_dst[0 * N + n], sd1 = s_dst[1 * N + n], sd2 = s_dst[2 * N + n];
  int e0 = offs[c], e1 = offs[c + 1];
  float m0 = -1e30f, m1 = -1e30f, m2 = -1e30f;
  for (int e = e0 + t; e < e1; e += 256) {
    int s = es_sorted[e];
    m0 = fmaxf(m0, lrelu(s_src[0 * N + s] + sd0));
    m1 = fmaxf(m1, lrelu(s_src[1 * N + s] + sd1));
    m2 = fmaxf(m2, lrelu(s_src[2 * N + s] + sd2));
  }
  __shared__ float red[3][256];
  red[0][t] = m0; red[1][t] = m1; red[2][t] = m2;
  __syncthreads();
  for (int s2 = 128; s2 > 0; s2 >>= 1) {
    if (t < s2) {
      red[0][t] = fmaxf(red[0][t], red[0][t + s2]);
      red[1][t] = fmaxf(red[1][t], red[1][t + s2]);
      red[2][t] = fmaxf(red[2][t], red[2][t + s2]);
    }
    __syncthreads();
  }
  m0 = red[0][0]; m1 = red[1][0]; m2 = red[2][0];
  float u0 = 0.f, u1 = 0.f, u2 = 0.f, z0 = 0.f, z1 = 0.f, z2 = 0.f;
  for (int e = e0; e < e1; e++) {
    int s = es_sorted[e];
    float xs = (t < 128) ? a0[(size_t)s * H + t] : a1[(size_t)s * H + (t - 128)];
    float ex0 = __expf(lrelu(s_src[0 * N + s] + sd0) - m0);
    float ex1 = __expf(lrelu(s_src[1 * N + s] + sd1) - m1);
    float ex2 = __expf(lrelu(s_src[2 * N + s] + sd2) - m2);
    z0 += ex0; z1 += ex1; z2 += ex2;
    u0 = fmaf(ex0, xs, u0); u1 = fmaf(ex1, xs, u1); u2 = fmaf(ex2, xs, u2);
  }
  size_t cb = (size_t)c * 256 + t;
  bool any = e1 > e0;
  agg_raw[0 * ((size_t)NB * 256) + cb] = any ? u0 / z0 : 0.f;
  agg_raw[1 * ((size_t)NB * 256) + cb] = any ? u1 / z1 : 0.f;
  agg_raw[2 * ((size_t)NB * 256) + cb] = any ? u2 / z2 : 0.f;
}

// ---------------- unified lin1 GEMM: 12288 agg rows + 4096 root rows -----------
__global__ __launch_bounds__(256)
void gemm_unified(const float* __restrict__ agg_raw,
                  const float* __restrict__ a0, const float* __restrict__ a1,
                  const int* __restrict__ node_list, const int* __restrict__ cntp,
                  const int* __restrict__ offs,
                  const unsigned short* __restrict__ Bth,
                  const unsigned short* __restrict__ Btl,
                  const float* __restrict__ bias,
                  unsigned short* __restrict__ aggxh, unsigned short* __restrict__ aggxl,
                  unsigned short* __restrict__ xsh, unsigned short* __restrict__ xsl) {
  const int t = threadIdx.x, lane = t & 63, wave = t >> 6;
  const int nl = lane & 15, quad = lane >> 4;
  const int rt = blockIdx.x * 64 + wave * 16;
  const int cnt = cntp[0];

  int gr = rt + nl;
  const float *pA, *pB;
  if (gr < 12288) {
    pA = agg_raw + (size_t)gr * 256;
    pB = pA + 128;
  } else {
    int cc = gr - 12288;
    int node = (cc < cnt) ? node_list[cc] : 0;
    pA = a0 + (size_t)node * H;
    pB = a1 + (size_t)node * H;
  }

  f32x4 acc[8];
  #pragma unroll
  for (int c = 0; c < 8; c++) acc[c] = (f32x4){0.f, 0.f, 0.f, 0.f};

  #pragma unroll
  for (int kt = 0; kt < 8; kt++) {
    const float* p = ((kt < 4) ? pA : pB) + (kt & 3) * 32 + quad * 8;
    bf16x8 ahi, alo;
    {
      float4 v0 = *(const float4*)p;
      float4 v1 = *(const float4*)(p + 4);
      float af[8] = {v0.x, v0.y, v0.z, v0.w, v1.x, v1.y, v1.z, v1.w};
      #pragma unroll
      for (int j = 0; j < 8; j++) {
        short h_, l_;
        split_trunc(af[j], &h_, &l_);
        ahi[j] = h_;
        alo[j] = l_;
      }
    }
    #pragma unroll
    for (int c = 0; c < 8; c++) {
      size_t boff = ((size_t)(kt * 8 + c) * 64 + lane) * 8;   // coalesced frag tile
      bf16x8 bh = *(const bf16x8*)(Bth + boff);
      bf16x8 bl = *(const bf16x8*)(Btl + boff);
      MFMA3(acc[c], ahi, alo, bh, bl);
    }
  }

  float bv[8];
  #pragma unroll
  for (int c = 0; c < 8; c++) bv[c] = bias[c * 16 + nl];

  #pragma unroll
  for (int r = 0; r < 4; r++) {
    int g2 = rt + quad * 4 + r;
    if (g2 < 12288) {
      int cc = g2 & 4095, h = g2 >> 12;
      bool he = offs[cc + 1] > offs[cc];
      size_t base = (size_t)h * NB * H + (size_t)cc * H;
      #pragma unroll
      for (int c = 0; c < 8; c++) {
        float val = acc[c][r] + (he ? bv[c] : 0.f);
        unsigned short vh, vl;
        split_rne(val, vh, vl);
        aggxh[base + c * 16 + nl] = vh;
        aggxl[base + c * 16 + nl] = vl;
      }
    } else {
      int cc = g2 - 12288;
      size_t base = (size_t)cc * H;
      #pragma unroll
      for (int c = 0; c < 8; c++) {
        float val = acc[c][r] + bv[c];
        unsigned short vh, vl;
        split_rne(val, vh, vl);
        xsh[base + c * 16 + nl] = vh;
        xsl[base + c * 16 + nl] = vl;
      }
    }
  }
}

// ---------------- fused 3-hop depth kernel -------------------------------------
// Round-7 residual: per-hop synchronous aggx stage (full HBM latency x3) and
// bank conflicts. Fixes here:
//  (1) aggx double-buffered via global_load_lds (fire-and-forget, CANNOT be
//      sunk by the scheduler -- round-4 lesson) issued one hop ahead;
//      vmcnt(0) only at hop end where the data had 2 GEMMs to arrive.
//  (2) A/X tiles stored unpadded [16][128] with a 16B-granule XOR swizzle
//      (chunk k at LDS slot k^(row&7)) applied on the pre-swizzled GLOBAL
//      source (rule: gload_lds dest must be linear; source is per-lane).
//      Read addr chunk-class = ((4kt+quad)^nl)&7 -> uniform 8 lanes/class ->
//      conflict-free ds_read_b128.
__global__ __launch_bounds__(512)
void hops3_fused(const unsigned short* __restrict__ aggxh,
                 const unsigned short* __restrict__ aggxl,
                 const unsigned short* __restrict__ xsh,
                 const unsigned short* __restrict__ xsl,
                 const unsigned short* __restrict__ gWh_all,
                 const unsigned short* __restrict__ gWl_all,
                 const float* __restrict__ gbias_all,
                 const unsigned short* __restrict__ CWh_all,
                 const unsigned short* __restrict__ CWl_all,
                 const float* __restrict__ lbias_all,
                 const unsigned short* __restrict__ L2h,
                 const unsigned short* __restrict__ L2l,
                 const float* __restrict__ lin2_b, float* __restrict__ l2out) {
  __shared__ unsigned short Ah[2][2048], Al[2][2048];     // aggx dbuf (swizzled)
  __shared__ unsigned short Xh[2048], Xl[2048];           // root x (swizzled)
  __shared__ unsigned short Th[16 * 136], Tl[16 * 136];   // htmp (padded)
  __shared__ unsigned short Hh[16 * 136], Hl[16 * 136];   // h state (padded)
  const int t = threadIdx.x, lane = t & 63, wave = t >> 6;  // wave 0..7
  const int nl = lane & 15, quad = lane >> 4;
  const int r0 = blockIdx.x * 16;
  const int f = wave * 16 + nl;

  // gload staging geometry: wave w stages KB (w&3) of array (hi if w<4 else lo)
  const int aj = wave & 3;
  const bool hiArr = wave < 4;
  const int ac = aj * 64 + lane;                 // 16B chunk index in 4KB array
  const int arow = ac >> 4, aks = ac & 15;
  const int akg = aks ^ (arow & 7);              // pre-swizzled global chunk
  const size_t asrc = (size_t)(r0 + arow) * H + akg * 8;

  // prologue: X + A(hop 0)
  GLOAD_LDS16((hiArr ? xsh : xsl) + asrc, (hiArr ? Xh : Xl) + aj * 512);
  GLOAD_LDS16((hiArr ? aggxh : aggxl) + asrc,
              (hiArr ? &Ah[0][0] : &Al[0][0]) + aj * 512);
  asm volatile("s_waitcnt vmcnt(0)" ::: "memory");
  __syncthreads();

  float creg[4] = {0.f, 0.f, 0.f, 0.f};   // c-state: rows quad*4+r, feature f
  f32x4 acc2[4];

  #pragma unroll
  for (int hop = 0; hop < 3; hop++) {
    const int buf = hop & 1;
    // prefetch next hop's aggx into the other buffer (fire-and-forget)
    if (hop < 2) {
      const unsigned short* sp =
          (hiArr ? aggxh : aggxl) + (size_t)(hop + 1) * NB * H + asrc;
      GLOAD_LDS16(sp, (hiArr ? &Ah[buf ^ 1][0] : &Al[buf ^ 1][0]) + aj * 512);
    }

    // ---- GEMM1: htmp = tanh(aggx @ gatW + gb); wave w -> col-tile w
    const unsigned short* gWh = gWh_all + hop * 16384;
    const unsigned short* gWl = gWl_all + hop * 16384;
    f32x4 acc1 = (f32x4){0.f, 0.f, 0.f, 0.f};
    #pragma unroll
    for (int kt = 0; kt < 4; kt++) {
      int sw = ((((kt << 2) + quad) ^ (nl & 7)) << 3);
      bf16x8 ah = *(const bf16x8*)&Ah[buf][nl * 128 + sw];
      bf16x8 al = *(const bf16x8*)&Al[buf][nl * 128 + sw];
      size_t boff = ((size_t)(kt * 8 + wave) * 64 + lane) * 8;
      bf16x8 bh = *(const bf16x8*)(gWh + boff);
      bf16x8 bl = *(const bf16x8*)(gWl + boff);
      MFMA3(acc1, ah, al, bh, bl);
    }
    {
      float bv = gbias_all[hop * H + f];
      #pragma unroll
      for (int r = 0; r < 4; r++) {
        int rl = quad * 4 + r;
        float v = tanhf(acc1[r] + bv);
        unsigned short vh, vl2;
        split_rne(v, vh, vl2);
        Th[rl * 136 + f] = vh;
        Tl[rl * 136 + f] = vl2;
      }
    }
    __syncthreads();

    // ---- GEMM2: gates[16x(4x128)] = [htmp|x1|h] @ CAT; wave w -> gates of ftile w
    const unsigned short* CWh = CWh_all + hop * 196608;
    const unsigned short* CWl = CWl_all + hop * 196608;
    #pragma unroll
    for (int g = 0; g < 4; g++) acc2[g] = (f32x4){0.f, 0.f, 0.f, 0.f};
    #pragma unroll
    for (int kt = 0; kt < 4; kt++) {          // K rows 0..127: htmp
      int kk = kt * 32 + quad * 8;
      bf16x8 ah = *(const bf16x8*)&Th[nl * 136 + kk];
      bf16x8 al = *(const bf16x8*)&Tl[nl * 136 + kk];
      #pragma unroll
      for (int g = 0; g < 4; g++) {
        size_t boff = ((size_t)(kt * 32 + wave * 4 + g) * 64 + lane) * 8;
        bf16x8 bh = *(const bf16x8*)(CWh + boff);
        bf16x8 bl = *(const bf16x8*)(CWl + boff);
        MFMA3(acc2[g], ah, al, bh, bl);
      }
    }
    #pragma unroll
    for (int kt = 0; kt < 4; kt++) {          // K rows 128..255 (x1), 256..383 (h)
      bf16x8 ah, al;
      if (hop == 0) {                         // x1 = root x; h = 0 (skip exactly)
        int sw = ((((kt << 2) + quad) ^ (nl & 7)) << 3);
        ah = *(const bf16x8*)&Xh[nl * 128 + sw];
        al = *(const bf16x8*)&Xl[nl * 128 + sw];
      } else {                                // x1 = h_prev = h (same fragment)
        int kk = kt * 32 + quad * 8;
        ah = *(const bf16x8*)&Hh[nl * 136 + kk];
        al = *(const bf16x8*)&Hl[nl * 136 + kk];
      }
      #pragma unroll
      for (int g = 0; g < 4; g++) {
        size_t boff = ((size_t)((kt + 4) * 32 + wave * 4 + g) * 64 + lane) * 8;
        bf16x8 bh = *(const bf16x8*)(CWh + boff);
        bf16x8 bl = *(const bf16x8*)(CWl + boff);
        MFMA3(acc2[g], ah, al, bh, bl);
      }
      if (hop > 0) {
        #pragma unroll
        for (int g = 0; g < 4; g++) {
          size_t boff = ((size_t)((kt + 8) * 32 + wave * 4 + g) * 64 + lane) * 8;
          bf16x8 bh = *(const bf16x8*)(CWh + boff);
          bf16x8 bl = *(const bf16x8*)(CWl + boff);
          MFMA3(acc2[g], ah, al, bh, bl);
        }
      }
    }
    __syncthreads();   // Hs reads (GEMM2) done before pointwise rewrites Hs

    // ---- LSTM pointwise; lane has all 4 gates of feature f
    {
      const float* lb = lbias_all + hop * 512;
      float b_i = lb[0 * 128 + f], b_f = lb[1 * 128 + f];
      float b_g = lb[2 * 128 + f], b_o = lb[3 * 128 + f];
      #pragma unroll
      for (int r = 0; r < 4; r++) {
        int rl = quad * 4 + r;
        float gi = acc2[0][r] + b_i;
        float gf = acc2[1][r] + b_f;
        float gg = acc2[2][r] + b_g;
        float go = acc2[3][r] + b_o;
        float cn = sigmoidf_(gf) * creg[r] + sigmoidf_(gi) * tanhf(gg);
        float hn = sigmoidf_(go) * tanhf(cn);
        creg[r] = cn;
        unsigned short vh, vl2;
        split_rne(hn, vh, vl2);
        Hh[rl * 136 + f] = vh;
        Hl[rl * 136 + f] = vl2;
      }
    }
    // prefetch landed long ago (2 GEMMs of cover); drain before next hop reads
    asm volatile("s_waitcnt vmcnt(0)" ::: "memory");
    __syncthreads();
  }

  // ---- GEMM3: lin2 on final h; wave w -> col-tile w
  f32x4 acc3 = (f32x4){0.f, 0.f, 0.f, 0.f};
  #pragma unroll
  for (int kt = 0; kt < 4; kt++) {
    int kk = kt * 32 + quad * 8;
    bf16x8 ah = *(const bf16x8*)&Hh[nl * 136 + kk];
    bf16x8 al = *(const bf16x8*)&Hl[nl * 136 + kk];
    size_t boff = ((size_t)(kt * 8 + wave) * 64 + lane) * 8;
    bf16x8 bh = *(const bf16x8*)(L2h + boff);
    bf16x8 bl = *(const bf16x8*)(L2l + boff);
    MFMA3(acc3, ah, al, bh, bl);
  }
  {
    float bv = lin2_b[f];
    #pragma unroll
    for (int r = 0; r < 4; r++) {
      int row = r0 + quad * 4 + r;
      l2out[(size_t)row * H + f] = acc3[r] + bv;
    }
  }
}

// ---------------- output gather ------------------------------------------------
__global__ void scatter_out(const float* __restrict__ l2out, const int* __restrict__ sel_map,
                            const int* __restrict__ root, const int* __restrict__ aggp,
                            float* __restrict__ out) {
  int id = blockIdx.x * 256 + threadIdx.x;
  if (id >= NB * H) return;
  int b = id >> 7, f = id & 127;
  int node = root[2 * b + (aggp[0] ? 0 : 1)];
  int c = sel_map[node];
  out[id] = l2out[(size_t)c * H + f];
}

// ==============================================================================
extern "C" void kernel_launch(void* const* d_in, const int* in_sizes, int n_in,
                              void* d_out, int out_size, void* d_ws, size_t ws_size,
                              hipStream_t stream) {
  const float* node_feat = (const float*)d_in[0];
  const float* send_embd = (const float*)d_in[1];
  const int*   edge_idx  = (const int*)d_in[2];
  const int*   root_idx  = (const int*)d_in[3];
  const int*   aggp      = (const int*)d_in[4];
  const float* lin1_W    = (const float*)d_in[5];
  const float* lin1_b    = (const float*)d_in[6];
  const float* gat_W     = (const float*)d_in[7];
  const float* gat_asrc  = (const float*)d_in[8];
  const float* gat_adst  = (const float*)d_in[9];
  const float* gat_b     = (const float*)d_in[10];
  const float* lstm_Wih  = (const float*)d_in[11];
  const float* lstm_Whh  = (const float*)d_in[12];
  const float* lstm_b    = (const float*)d_in[13];
  const float* lin2_W    = (const float*)d_in[14];
  const float* lin2_b    = (const float*)d_in[15];
  float* out = (float*)d_out;

  char* ws = (char*)d_ws;
  float* agg_raw = (float*)(ws + OFF_AGGRAW);
  float* wv2     = (float*)(ws + OFF_WV2);
  float* c2      = (float*)(ws + OFF_C2);
  int*   plist   = (int*)(ws + OFF_PLIST);
  float* s_src   = (float*)(ws + OFF_SSRC);
  float* s_dst   = (float*)(ws + OFF_SDST);
  float* wvec    = (float*)(ws + OFF_WVEC);
  int*   sel_map = (int*)(ws + OFF_SELMAP);
  int*   nodelst = (int*)(ws + OFF_NODELST);
  int*   cnt     = (int*)(ws + OFF_CNT);
  int*   deg     = (int*)(ws + OFF_DEG);
  int*   offs    = (int*)(ws + OFF_OFFS);
  int*   cursor  = (int*)(ws + OFF_CURSOR);
  int*   esort   = (int*)(ws + OFF_ESORT);
  unsigned short* aggxh = (unsigned short*)(ws + OFF_AGGXH);
  unsigned short* aggxl = (unsigned short*)(ws + OFF_AGGXL);
  unsigned short* xsh   = (unsigned short*)(ws + OFF_XSH);
  unsigned short* xsl   = (unsigned short*)(ws + OFF_XSL);
  float* l2out   = (float*)(ws + OFF_L2OUT);
  unsigned short* whi = (unsigned short*)(ws + OFF_WHI);
  unsigned short* wlo = (unsigned short*)(ws + OFF_WLO);

  // needed-row scratch carved from the aggx region: consumed by score_pass,
  // which runs strictly before gemm_unified writes aggxh/aggxl over it.
  int* need_flag = (int*)(ws + OFF_AGGXH);            // [N]
  int* need_list = need_flag + N;                     // [N]
  int* need_cnt  = cnt + 1;                           // zeroed by init_ws
  int* plist_cnt = cnt + 2;                           // zeroed by init_ws

  init_ws<<<512, 256, 0, stream>>>(sel_map, deg, cursor, cnt, need_flag);
  prep_kernel<<<6 + (WTOT + 255) / 256, 256, 0, stream>>>(
      gat_W, gat_asrc, gat_adst, wvec, lin1_W, lstm_Wih, lstm_Whh, lin2_W, whi, wlo);
  prep2_kernel<<<6, 256, 0, stream>>>(lin1_W, lin1_b, wvec, wv2, c2);
  roots_assign<<<(NB + 255) / 256, 256, 0, stream>>>(root_idx, aggp, sel_map, nodelst, cnt,
                                                     need_flag);

  // edge CSR: ONE full-E scan (count + pair compaction + need marking)
  const int egrid = (E + 256 * EPT - 1) / (256 * EPT);
  edge_pass1<<<egrid, 256, 0, stream>>>(edge_idx, sel_map, deg, plist, plist_cnt,
                                        need_flag);
  compact_need<<<(N + 255) / 256, 256, 0, stream>>>(need_flag, need_list, need_cnt);
  scan_kernel<<<1, 1024, 0, stream>>>(deg, offs);
  edge_pass2<<<256, 256, 0, stream>>>(plist, plist_cnt, offs, cursor, esort);

  // scores over needed rows (pure gather+dot; no lin1 GEMM over sources)
  score_pass<<<(N + 15) / 16, 256, 0, stream>>>(
      node_feat, send_embd, wv2, c2, s_src, s_dst, need_list, need_cnt);

  // raw-feature softmax aggregation per selected destination
  gat_node_kernel<<<NB, 256, 0, stream>>>(nodelst, cnt, offs, esort,
                                          node_feat, send_embd, s_src, s_dst, agg_raw);

  // one lin1 GEMM over 12288 agg rows + 4096 root rows
  gemm_unified<<<256, 256, 0, stream>>>(
      agg_raw, node_feat, send_embd, nodelst, cnt, offs,
      whi + WOFF_L1, wlo + WOFF_L1, lin1_b,
      aggxh, aggxl, xsh, xsl);

  // all 3 hops + lin2, fused (per-row recurrence => no grid sync needed)
  hops3_fused<<<NB / 16, 512, 0, stream>>>(
      aggxh, aggxl, xsh, xsl,
      whi + WOFF_GAT, wlo + WOFF_GAT, gat_b,
      whi + WOFF_CAT, wlo + WOFF_CAT, lstm_b,
      whi + WOFF_L2, wlo + WOFF_L2, lin2_b, l2out);

  scatter_out<<<(NB * H + 255) / 256, 256, 0, stream>>>(l2out, sel_map, root_idx, aggp, out);
}

// Round 9
// 311.455 us; speedup vs baseline: 1.2428x; 1.0324x over previous
//
#include <hip/hip_runtime.h>

// Problem constants (match reference)
constexpr int N  = 100000;   // nodes
constexpr int E  = 1600000;  // edges
constexpr int H  = 128;      // hidden
constexpr int NB = 4096;     // root pairs
constexpr int HOPS = 3;
constexpr int EPT = 8;       // edges per thread in E-scans (MLP)

// Swizzled converted-weight buffer (element offsets into whi/wlo ushort arrays).
constexpr int WOFF_L1  = 0;                      // numC=8,  numT=8  (K=256)
constexpr int WOFF_GAT = 32768;                  // 3 x numC=8,  numT=4
constexpr int WOFF_CAT = 81920;                  // 3 x numC=32, numT=12 (gate-perm)
constexpr int WOFF_L2  = 671744;                 // numC=8,  numT=4
constexpr int WTOT     = 688128;

// ---------------- workspace layout (byte offsets, 256B aligned) ---------------
constexpr size_t ALIGN = 256;
constexpr size_t alup(size_t x) { return (x + ALIGN - 1) & ~(ALIGN - 1); }

constexpr size_t OFF_X       = 0;                                        // repurposed (below)
constexpr size_t OFF_SSRC    = alup(OFF_X + (size_t)N * H * 4);          // [3][N] f32
constexpr size_t OFF_SDST    = alup(OFF_SSRC + (size_t)3 * N * 4);       // [3][N] f32
constexpr size_t OFF_WVEC    = alup(OFF_SDST + (size_t)3 * N * 4);       // [6][128] f32
constexpr size_t OFF_SELMAP  = alup(OFF_WVEC + 6 * H * 4);               // [N] int
constexpr size_t OFF_NODELST = alup(OFF_SELMAP + (size_t)N * 4);         // [4096] int
constexpr size_t OFF_CNT     = alup(OFF_NODELST + NB * 4);               // [64] int
constexpr size_t OFF_DEG     = alup(OFF_CNT + 256);                      // [4096] int
constexpr size_t OFF_OFFS    = alup(OFF_DEG + NB * 4);                   // [4097] int
constexpr size_t OFF_CURSOR  = alup(OFF_OFFS + (NB + 1) * 4);            // [4096] int
constexpr size_t OFF_ESORT   = alup(OFF_CURSOR + NB * 4);                // [E] int
constexpr size_t OFF_AGGXH   = alup(OFF_ESORT + (size_t)E * 4);          // [3][4096][128] us
constexpr size_t OFF_AGGXL   = alup(OFF_AGGXH + (size_t)3 * NB * H * 2);
constexpr size_t OFF_XSH     = alup(OFF_AGGXL + (size_t)3 * NB * H * 2); // [4096][128] us
constexpr size_t OFF_XSL     = alup(OFF_XSH + (size_t)NB * H * 2);
constexpr size_t OFF_L2OUT   = alup(OFF_XSL + (size_t)NB * H * 2);       // [4096][128] f32
constexpr size_t OFF_WHI     = alup(OFF_L2OUT + (size_t)NB * H * 4);     // [WTOT] us
constexpr size_t OFF_WLO     = alup(OFF_WHI + (size_t)WTOT * 2);         // [WTOT] us

// Repurposed old-x region (51.2 MB): raw agg + folded score vecs + pair list
constexpr size_t OFF_AGGRAW  = OFF_X;                                    // [3*4096][256] f32 (12.6MB)
constexpr size_t OFF_WV2     = OFF_X + (size_t)16 * 1024 * 1024;         // [6][256] f32
constexpr size_t OFF_C2     = OFF_WV2 + 6 * 256 * 4;                     // [6] f32
constexpr size_t OFF_PLIST  = OFF_X + (size_t)20 * 1024 * 1024;          // [<=E] int (6.4MB max)

__device__ __forceinline__ float lrelu(float v) { return v > 0.f ? v : 0.2f * v; }
__device__ __forceinline__ float sigmoidf_(float v) { return 1.f / (1.f + __expf(-v)); }

__device__ __forceinline__ unsigned short f2bf(float f) {
  unsigned u = __float_as_uint(f);
  unsigned r = (u + 0x7FFFu + ((u >> 16) & 1u)) >> 16;
  return (unsigned short)r;
}
__device__ __forceinline__ float bf2f(unsigned short h) {
  return __uint_as_float((unsigned)h << 16);
}
__device__ __forceinline__ void split_rne(float f, unsigned short& hi, unsigned short& lo) {
  unsigned short hh = f2bf(f);
  hi = hh;
  lo = f2bf(f - bf2f(hh));
}
// 4-op truncation split (GEMM hot path); pointer outs (vector elems can't bind refs)
__device__ __forceinline__ void split_trunc(float f, short* hi, short* lo) {
  unsigned u = __float_as_uint(f);
  *hi = (short)(u >> 16);
  float r = f - __uint_as_float(u & 0xFFFF0000u);
  *lo = (short)(__float_as_uint(r) >> 16);
}

typedef short bf16x8 __attribute__((ext_vector_type(8)));
typedef float f32x4  __attribute__((ext_vector_type(4)));

#define MFMA3(ACC, AH, AL, BH, BL)                                               \
  ACC = __builtin_amdgcn_mfma_f32_16x16x32_bf16(AH, BH, ACC, 0, 0, 0);           \
  ACC = __builtin_amdgcn_mfma_f32_16x16x32_bf16(AH, BL, ACC, 0, 0, 0);           \
  ACC = __builtin_amdgcn_mfma_f32_16x16x32_bf16(AL, BH, ACC, 0, 0, 0);

// fire-and-forget 16B/lane global->LDS copy (dest = L + lane*16, wave-uniform L)
#define GLOAD_LDS16(G, L)                                                        \
  __builtin_amdgcn_global_load_lds(                                              \
      (const __attribute__((address_space(1))) void*)(G),                        \
      (__attribute__((address_space(3))) void*)(L), 16, 0, 0)

#define VMCNT0  asm volatile("s_waitcnt vmcnt(0)" ::: "memory")
#define VMCNT4  asm volatile("s_waitcnt vmcnt(4)" ::: "memory")
#define VMCNT8  asm volatile("s_waitcnt vmcnt(8)" ::: "memory")
#define VMCNT12 asm volatile("s_waitcnt vmcnt(12)" ::: "memory")
#define LGKM0   asm volatile("s_waitcnt lgkmcnt(0)" ::: "memory")

// ---------------- init: replaces memsets ---------------------------------------
__global__ void init_ws(int* __restrict__ sel_map, int* __restrict__ deg,
                        int* __restrict__ cursor, int* __restrict__ cnt,
                        int* __restrict__ need_flag) {
  int i = blockIdx.x * 256 + threadIdx.x;
  int stride = gridDim.x * 256;
  for (int n = i; n < N; n += stride) { sel_map[n] = -1; need_flag[n] = 0; }
  for (int n = i; n < NB; n += stride) { deg[n] = 0; cursor[n] = 0; }
  if (i < 64) cnt[i] = 0;
}

// ---------------- prep: wvec + weight convert to swizzled fragment tiles -------
__global__ void prep_kernel(const float* __restrict__ gat_W,
                            const float* __restrict__ a_src,
                            const float* __restrict__ a_dst,
                            float* __restrict__ wvec,
                            const float* __restrict__ lin1_W,
                            const float* __restrict__ Wih,
                            const float* __restrict__ Whh,
                            const float* __restrict__ lin2_W,
                            unsigned short* __restrict__ whi,
                            unsigned short* __restrict__ wlo) {
  if (blockIdx.x < 6) {
    int i = blockIdx.x >> 1, which = blockIdx.x & 1;
    int k = threadIdx.x;
    __shared__ float av[H];
    if (k < H) av[k] = which ? a_dst[i * H + k] : a_src[i * H + k];
    __syncthreads();
    if (k >= H) return;
    const float* Wr = gat_W + (size_t)i * H * H + (size_t)k * H;
    float s = 0.f;
    #pragma unroll 8
    for (int j = 0; j < H; j++) s = fmaf(Wr[j], av[j], s);
    wvec[(i * 2 + which) * H + k] = s;
    return;
  }
  int idx = (blockIdx.x - 6) * 256 + threadIdx.x;
  if (idx >= WTOT) return;
  float v;
  if (idx < WOFF_GAT) {                      // lin1: numC=8, K=256
    int rel = idx;
    int e = rel & 7, lane = (rel >> 3) & 63, tile = rel >> 9;
    int nl = lane & 15, quad = lane >> 4;
    int c = tile & 7, t = tile >> 3;
    int n = c * 16 + nl, k = t * 32 + quad * 8 + e;
    v = lin1_W[k * 128 + n];
  } else if (idx < WOFF_CAT) {               // gat: 3 x numC=8, K=128
    int rel = idx - WOFF_GAT;
    int hop = rel / 16384; rel %= 16384;
    int e = rel & 7, lane = (rel >> 3) & 63, tile = rel >> 9;
    int nl = lane & 15, quad = lane >> 4;
    int c = tile & 7, t = tile >> 3;
    int n = c * 16 + nl, k = t * 32 + quad * 8 + e;
    v = gat_W[hop * 16384 + k * 128 + n];
  } else if (idx < WOFF_L2) {                // CAT: 3 x numC=32, K=384, gate-perm
    int rel = idx - WOFF_CAT;
    int hop = rel / 196608; rel %= 196608;
    int e = rel & 7, lane = (rel >> 3) & 63, tile = rel >> 9;
    int nl = lane & 15, quad = lane >> 4;
    int c = tile & 31, t = tile >> 5;
    int ftile = c >> 2, g = c & 3;           // virtual col tile -> (feature-tile, gate)
    int col = g * 128 + ftile * 16 + nl;     // original column in [Wih;Whh]
    int k = t * 32 + quad * 8 + e;
    v = (k < 256) ? Wih[hop * 131072 + k * 512 + col]
                  : Whh[hop * 65536 + (k - 256) * 512 + col];
  } else {                                   // lin2: numC=8, K=128
    int rel = idx - WOFF_L2;
    int e = rel & 7, lane = (rel >> 3) & 63, tile = rel >> 9;
    int nl = lane & 15, quad = lane >> 4;
    int c = tile & 7, t = tile >> 3;
    int n = c * 16 + nl, k = t * 32 + quad * 8 + e;
    v = lin2_W[k * 128 + n];
  }
  unsigned short hh, ll;
  split_rne(v, hh, ll);
  whi[idx] = hh;
  wlo[idx] = ll;
}

// ---------------- prep2: fold lin1 into score vectors --------------------------
__global__ void prep2_kernel(const float* __restrict__ lin1_W,
                             const float* __restrict__ lin1_b,
                             const float* __restrict__ wvec,
                             float* __restrict__ wv2, float* __restrict__ c2) {
  int v = blockIdx.x;          // 0..5
  int j = threadIdx.x;         // 0..255 (row of W1)
  __shared__ float wv[H];
  if (j < H) wv[j] = wvec[v * H + j];
  __syncthreads();
  const float* Wr = lin1_W + (size_t)j * H;
  float s = 0.f;
  #pragma unroll 8
  for (int m = 0; m < H; m++) s = fmaf(Wr[m], wv[m], s);
  wv2[v * 256 + j] = s;
  if (j == 0) {
    float cc = 0.f;
    for (int m = 0; m < H; m++) cc = fmaf(lin1_b[m], wv[m], cc);
    c2[v] = cc;
  }
}

// ---------------- roots: mark + compact-id assign ------------------------------
__global__ void roots_assign(const int* __restrict__ root, const int* __restrict__ aggp,
                             int* __restrict__ sel_map, int* __restrict__ node_list,
                             int* __restrict__ cnt, int* __restrict__ need_flag) {
  int b = blockIdx.x * 256 + threadIdx.x;
  if (b >= NB) return;
  int node = root[2 * b + (aggp[0] ? 0 : 1)];
  need_flag[node] = 1;                       // plain store, idempotent
  int old = atomicCAS(&sel_map[node], -1, -2);
  if (old == -1) {
    int c = atomicAdd(cnt, 1);
    sel_map[node] = c;
    node_list[c] = node;
  }
}

// ---------------- edge pass 1: count + pair compaction + need marking ----------
__global__ void edge_pass1(const int* __restrict__ ei, const int* __restrict__ sel_map,
                           int* __restrict__ deg, int* __restrict__ plist,
                           int* __restrict__ plist_cnt, int* __restrict__ need_flag) {
  __shared__ int lcnt, lbase;
  const int T = gridDim.x * 256;
  const int tid = threadIdx.x, lane = tid & 63;
  if (tid == 0) lcnt = 0;
  __syncthreads();
  const int base = blockIdx.x * 256 + tid;
  int dn[EPT], sn[EPT], pos[EPT];
  #pragma unroll
  for (int k = 0; k < EPT; k++) {
    int e = base + k * T;
    dn[k] = (e < E) ? ei[E + e] : -1;
  }
  #pragma unroll
  for (int k = 0; k < EPT; k++) {
    if (dn[k] >= 0) dn[k] = sel_map[dn[k]];
  }
  #pragma unroll
  for (int k = 0; k < EPT; k++) {
    int e = base + k * T;
    sn[k] = (dn[k] >= 0) ? ei[e] : 0;
  }
  #pragma unroll
  for (int k = 0; k < EPT; k++) {
    bool f = dn[k] >= 0;
    if (f) { atomicAdd(&deg[dn[k]], 1); need_flag[sn[k]] = 1; }
    unsigned long long mask = __ballot(f);
    int wc = __popcll(mask);
    int wb = 0;
    if (lane == 0 && wc > 0) wb = atomicAdd(&lcnt, wc);   // LDS atomic
    wb = __shfl(wb, 0);
    pos[k] = f ? (wb + __popcll(mask & ((1ull << lane) - 1ull))) : -1;
  }
  __syncthreads();
  if (tid == 0) lbase = (lcnt > 0) ? atomicAdd(plist_cnt, lcnt) : 0;
  __syncthreads();
  #pragma unroll
  for (int k = 0; k < EPT; k++) {
    if (pos[k] >= 0) plist[lbase + pos[k]] = (dn[k] << 17) | sn[k];
  }
}

__global__ __launch_bounds__(1024)
void scan_kernel(const int* __restrict__ deg, int* __restrict__ offs) {
  __shared__ int part[1024];
  int t = threadIdx.x;
  int base = t * 4;
  int v0 = deg[base], v1 = deg[base + 1], v2 = deg[base + 2], v3 = deg[base + 3];
  int s = v0 + v1 + v2 + v3;
  part[t] = s;
  __syncthreads();
  for (int off = 1; off < 1024; off <<= 1) {
    int tmp = (t >= off) ? part[t - off] : 0;
    __syncthreads();
    part[t] += tmp;
    __syncthreads();
  }
  int run = part[t] - s;
  offs[base] = run; run += v0;
  offs[base + 1] = run; run += v1;
  offs[base + 2] = run; run += v2;
  offs[base + 3] = run;
  if (t == 1023) offs[NB] = part[1023];
}

// ---------------- edge pass 2: scatter from compact pair list (~64K) -----------
__global__ void edge_pass2(const int* __restrict__ plist, const int* __restrict__ plist_cnt,
                           const int* __restrict__ offs, int* __restrict__ cursor,
                           int* __restrict__ es_sorted) {
  int np = plist_cnt[0];
  for (int i = blockIdx.x * 256 + threadIdx.x; i < np; i += gridDim.x * 256) {
    int pk = plist[i];
    int d = pk >> 17, s = pk & 0x1FFFF;
    int p = atomicAdd(&cursor[d], 1);
    es_sorted[offs[d] + p] = s;
  }
}

// ---------------- needed-set compaction (wave-ballot, ~1.5K atomics total) -----
__global__ void compact_need(const int* __restrict__ need_flag,
                             int* __restrict__ need_list, int* __restrict__ need_cnt) {
  int i = blockIdx.x * 256 + threadIdx.x;
  bool f = (i < N) && (need_flag[i] != 0);
  unsigned long long mask = __ballot(f);
  int lane = threadIdx.x & 63;
  int wcnt = __popcll(mask);
  int base = 0;
  if (lane == 0 && wcnt > 0) base = atomicAdd(need_cnt, wcnt);
  base = __shfl(base, 0);
  if (f) {
    int prefix = __popcll(mask & ((1ull << lane) - 1ull));
    need_list[base + prefix] = i;
  }
}

// ---------------- score pass: s = cat . wv2 + c2 over needed rows --------------
__global__ __launch_bounds__(256)
void score_pass(const float* __restrict__ a0, const float* __restrict__ a1,
                const float* __restrict__ wv2, const float* __restrict__ c2,
                float* __restrict__ s_src, float* __restrict__ s_dst,
                const int* __restrict__ need_list, const int* __restrict__ need_cnt) {
  const int nneed = need_cnt[0];
  if (blockIdx.x * 16 >= nneed) return;
  __shared__ float Ws[6 * 256];
  __shared__ float C2s[6];
  const int t = threadIdx.x, lane = t & 63, wave = t >> 6;
  const int nl = lane & 15;
  #pragma unroll
  for (int v = 0; v < 6; v++) Ws[v * 256 + t] = wv2[v * 256 + t];
  if (t < 6) C2s[t] = c2[t];
  __syncthreads();

  int r = blockIdx.x * 16 + wave * 4 + (lane >> 4);
  int row = (r < nneed) ? need_list[r] : -1;
  int rc = (row < 0) ? 0 : row;
  const float* src = (nl < 8) ? (a0 + (size_t)rc * H + nl * 16)
                              : (a1 + (size_t)rc * H + (nl - 8) * 16);
  float4 va[4];
  #pragma unroll
  for (int q = 0; q < 4; q++) va[q] = ((const float4*)src)[q];

  float p[6] = {0.f, 0.f, 0.f, 0.f, 0.f, 0.f};
  #pragma unroll
  for (int q = 0; q < 4; q++) {
    float4 v4 = va[q];
    #pragma unroll
    for (int v = 0; v < 6; v++) {
      float4 w4 = *(const float4*)&Ws[v * 256 + nl * 16 + q * 4];
      p[v] = fmaf(v4.x, w4.x, p[v]);
      p[v] = fmaf(v4.y, w4.y, p[v]);
      p[v] = fmaf(v4.z, w4.z, p[v]);
      p[v] = fmaf(v4.w, w4.w, p[v]);
    }
  }
  #pragma unroll
  for (int m = 1; m < 16; m <<= 1)
    #pragma unroll
    for (int v = 0; v < 6; v++) p[v] += __shfl_xor(p[v], m);
  if (nl == 0 && row >= 0) {
    #pragma unroll
    for (int h3 = 0; h3 < 3; h3++) {
      s_src[h3 * N + row] = p[2 * h3 + 0] + C2s[2 * h3 + 0];
      s_dst[h3 * N + row] = p[2 * h3 + 1] + C2s[2 * h3 + 1];
    }
  }
}

// ---------------- per-destination GAT softmax aggregation (RAW features) -------
__global__ __launch_bounds__(256)
void gat_node_kernel(const int* __restrict__ node_list, const int* __restrict__ cntp,
                     const int* __restrict__ offs, const int* __restrict__ es_sorted,
                     const float* __restrict__ a0, const float* __restrict__ a1,
                     const float* __restrict__ s_src, const float* __restrict__ s_dst,
                     float* __restrict__ agg_raw) {
  int c = blockIdx.x;
  if (c >= cntp[0]) return;
  int t = threadIdx.x;
  int n = node_list[c];
  float sd0 = s_dst[0 * N + n], sd1 = s_dst[1 * N + n], sd2 = s_dst[2 * N + n];
  int e0 = offs[c], e1 = offs[c + 1];
  float m0 = -1e30f, m1 = -1e30f, m2 = -1e30f;
  for (int e = e0 + t; e < e1; e += 256) {
    int s = es_sorted[e];
    m0 = fmaxf(m0, lrelu(s_src[0 * N + s] + sd0));
    m1 = fmaxf(m1, lrelu(s_src[1 * N + s] + sd1));
    m2 = fmaxf(m2, lrelu(s_src[2 * N + s] + sd2));
  }
  __shared__ float red[3][256];
  red[0][t] = m0; red[1][t] = m1; red[2][t] = m2;
  __syncthreads();
  for (int s2 = 128; s2 > 0; s2 >>= 1) {
    if (t < s2) {
      red[0][t] = fmaxf(red[0][t], red[0][t + s2]);
      red[1][t] = fmaxf(red[1][t], red[1][t + s2]);
      red[2][t] = fmaxf(red[2][t], red[2][t + s2]);
    }
    __syncthreads();
  }
  m0 = red[0][0]; m1 = red[1][0]; m2 = red[2][0];
  float u0 = 0.f, u1 = 0.f, u2 = 0.f, z0 = 0.f, z1 = 0.f, z2 = 0.f;
  for (int e = e0; e < e1; e++) {
    int s = es_sorted[e];
    float xs = (t < 128) ? a0[(size_t)s * H + t] : a1[(size_t)s * H + (t - 128)];
    float ex0 = __expf(lrelu(s_src[0 * N + s] + sd0) - m0);
    float ex1 = __expf(lrelu(s_src[1 * N + s] + sd1) - m1);
    float ex2 = __expf(lrelu(s_src[2 * N + s] + sd2) - m2);
    z0 += ex0; z1 += ex1; z2 += ex2;
    u0 = fmaf(ex0, xs, u0); u1 = fmaf(ex1, xs, u1); u2 = fmaf(ex2, xs, u2);
  }
  size_t cb = (size_t)c * 256 + t;
  bool any = e1 > e0;
  agg_raw[0 * ((size_t)NB * 256) + cb] = any ? u0 / z0 : 0.f;
  agg_raw[1 * ((size_t)NB * 256) + cb] = any ? u1 / z1 : 0.f;
  agg_raw[2 * ((size_t)NB * 256) + cb] = any ? u2 / z2 : 0.f;
}

// ---------------- unified lin1 GEMM: 12288 agg rows + 4096 root rows -----------
__global__ __launch_bounds__(256)
void gemm_unified(const float* __restrict__ agg_raw,
                  const float* __restrict__ a0, const float* __restrict__ a1,
                  const int* __restrict__ node_list, const int* __restrict__ cntp,
                  const int* __restrict__ offs,
                  const unsigned short* __restrict__ Bth,
                  const unsigned short* __restrict__ Btl,
                  const float* __restrict__ bias,
                  unsigned short* __restrict__ aggxh, unsigned short* __restrict__ aggxl,
                  unsigned short* __restrict__ xsh, unsigned short* __restrict__ xsl) {
  const int t = threadIdx.x, lane = t & 63, wave = t >> 6;
  const int nl = lane & 15, quad = lane >> 4;
  const int rt = blockIdx.x * 64 + wave * 16;
  const int cnt = cntp[0];

  int gr = rt + nl;
  const float *pA, *pB;
  if (gr < 12288) {
    pA = agg_raw + (size_t)gr * 256;
    pB = pA + 128;
  } else {
    int cc = gr - 12288;
    int node = (cc < cnt) ? node_list[cc] : 0;
    pA = a0 + (size_t)node * H;
    pB = a1 + (size_t)node * H;
  }

  f32x4 acc[8];
  #pragma unroll
  for (int c = 0; c < 8; c++) acc[c] = (f32x4){0.f, 0.f, 0.f, 0.f};

  #pragma unroll
  for (int kt = 0; kt < 8; kt++) {
    const float* p = ((kt < 4) ? pA : pB) + (kt & 3) * 32 + quad * 8;
    bf16x8 ahi, alo;
    {
      float4 v0 = *(const float4*)p;
      float4 v1 = *(const float4*)(p + 4);
      float af[8] = {v0.x, v0.y, v0.z, v0.w, v1.x, v1.y, v1.z, v1.w};
      #pragma unroll
      for (int j = 0; j < 8; j++) {
        short h_, l_;
        split_trunc(af[j], &h_, &l_);
        ahi[j] = h_;
        alo[j] = l_;
      }
    }
    #pragma unroll
    for (int c = 0; c < 8; c++) {
      size_t boff = ((size_t)(kt * 8 + c) * 64 + lane) * 8;   // coalesced frag tile
      bf16x8 bh = *(const bf16x8*)(Bth + boff);
      bf16x8 bl = *(const bf16x8*)(Btl + boff);
      MFMA3(acc[c], ahi, alo, bh, bl);
    }
  }

  float bv[8];
  #pragma unroll
  for (int c = 0; c < 8; c++) bv[c] = bias[c * 16 + nl];

  #pragma unroll
  for (int r = 0; r < 4; r++) {
    int g2 = rt + quad * 4 + r;
    if (g2 < 12288) {
      int cc = g2 & 4095, h = g2 >> 12;
      bool he = offs[cc + 1] > offs[cc];
      size_t base = (size_t)h * NB * H + (size_t)cc * H;
      #pragma unroll
      for (int c = 0; c < 8; c++) {
        float val = acc[c][r] + (he ? bv[c] : 0.f);
        unsigned short vh, vl;
        split_rne(val, vh, vl);
        aggxh[base + c * 16 + nl] = vh;
        aggxl[base + c * 16 + nl] = vl;
      }
    } else {
      int cc = g2 - 12288;
      size_t base = (size_t)cc * H;
      #pragma unroll
      for (int c = 0; c < 8; c++) {
        float val = acc[c][r] + bv[c];
        unsigned short vh, vl;
        split_rne(val, vh, vl);
        xsh[base + c * 16 + nl] = vh;
        xsl[base + c * 16 + nl] = vl;
      }
    }
  }
}

// ---------------- fused 3-hop depth kernel (pipelined B) -----------------------
// Round-8 diagnosis: VGPR=72 => compiler gave the B-stream ZERO prefetch
// buffering; ~192 L2 B-loads/wave/hop serialized at ~200cyc each = ~115K cyc
// == measured 120K. Fix (T3/T4): per-wave 3-slot LDS B pipeline fed by
// global_load_lds (cannot be sunk), counted vmcnt(8) per unit, raw s_barrier
// (+explicit lgkmcnt) so loads survive barriers. A single-buffered with
// next-hop prefetch folded into the counted stream. T/H use the same
// 128-stride XOR-chunk layout as A so all A-operand reads share one formula.
__global__ __launch_bounds__(512, 1)
void hops3_fused(const unsigned short* __restrict__ aggxh,
                 const unsigned short* __restrict__ aggxl,
                 const unsigned short* __restrict__ xsh,
                 const unsigned short* __restrict__ xsl,
                 const unsigned short* __restrict__ gWh_all,
                 const unsigned short* __restrict__ gWl_all,
                 const float* __restrict__ gbias_all,
                 const unsigned short* __restrict__ CWh_all,
                 const unsigned short* __restrict__ CWl_all,
                 const float* __restrict__ lbias_all,
                 const unsigned short* __restrict__ L2h,
                 const unsigned short* __restrict__ L2l,
                 const float* __restrict__ lin2_b, float* __restrict__ l2out) {
  __shared__ unsigned short Ah[2048], Al[2048];     // aggx (swizzled, 1 hop)
  __shared__ unsigned short A2h[2048], A2l[2048];   // root x (hop0 x1)
  __shared__ unsigned short Th_[2048], Tl_[2048];   // htmp (swizzled)
  __shared__ unsigned short Hh_[2048], Hl_[2048];   // h state (swizzled)
  __shared__ unsigned short Bst[8][3 * 2048];       // per-wave 3x4KB B slots
  const int t = threadIdx.x, lane = t & 63, wave = t >> 6;  // wave 0..7
  const int nl = lane & 15, quad = lane >> 4;
  const int r0 = blockIdx.x * 16;
  const int f = wave * 16 + nl;
  unsigned short* BstW = &Bst[wave][0];

  // A/X staging geometry: wave w stages KB (w&3) of (hi if w<4 else lo)
  const int aj = wave & 3;
  const bool hiArr = wave < 4;
  const int ac = aj * 64 + lane;                 // 16B chunk index in 4KB array
  const int arow = ac >> 4, aks = ac & 15;
  const int akg = aks ^ (arow & 7);              // pre-swizzled global chunk
  const size_t asrc = (size_t)(r0 + arow) * H + akg * 8;

  // T/H write address for (row rl, col f): chunk XOR swizzle matching A-reads
  const int fc = f >> 3, fe = f & 7;

  // prologue: A(hop0) + X staged once (1 gload each per wave)
  GLOAD_LDS16((hiArr ? aggxh : aggxl) + asrc, (hiArr ? Ah : Al) + aj * 512);
  GLOAD_LDS16((hiArr ? xsh : xsl) + asrc, (hiArr ? A2h : A2l) + aj * 512);

  float creg[4] = {0.f, 0.f, 0.f, 0.f};
  f32x4 acc2[4];

  for (int hop = 0; hop < 3; hop++) {
    const unsigned short* gWh = gWh_all + hop * 16384;
    const unsigned short* gWl = gWl_all + hop * 16384;
    const unsigned short* CWh = CWh_all + hop * 196608;
    const unsigned short* CWl = CWl_all + hop * 196608;
    const int KT = (hop == 0) ? 8 : 12;
    const int NU = 2 * KT;

    // hop-entry: drain H ds_writes; load biases behind a vmcnt fence so the
    // counted B pipeline below sees exact counts
    LGKM0;
    float gbv = gbias_all[hop * H + f];
    float b_i = lbias_all[hop * 512 + 0 * 128 + f];
    float b_f = lbias_all[hop * 512 + 1 * 128 + f];
    float b_g = lbias_all[hop * 512 + 2 * 128 + f];
    float b_o = lbias_all[hop * 512 + 3 * 128 + f];
    VMCNT0;   // also drains A/X (hop0) or confirms A-prefetch (hop>0)

    // stage slot0 = G1{kt0,1}, slot1 = G1{kt2,3}, slot2 = G2 unit0
    {
      const unsigned short* b0 = gWh + (0 * 8 + wave) * 512 + lane * 8;
      const unsigned short* c0 = gWl + (0 * 8 + wave) * 512 + lane * 8;
      GLOAD_LDS16(b0, BstW);
      GLOAD_LDS16(c0, BstW + 512);
      GLOAD_LDS16(b0 + 8 * 512, BstW + 1024);
      GLOAD_LDS16(c0 + 8 * 512, BstW + 1536);
      const unsigned short* b2 = gWh + (2 * 8 + wave) * 512 + lane * 8;
      const unsigned short* c2 = gWl + (2 * 8 + wave) * 512 + lane * 8;
      GLOAD_LDS16(b2, BstW + 2048);
      GLOAD_LDS16(c2, BstW + 2560);
      GLOAD_LDS16(b2 + 8 * 512, BstW + 3072);
      GLOAD_LDS16(c2 + 8 * 512, BstW + 3584);
      const unsigned short* b4 = CWh + (0 * 32 + wave * 4 + 0) * 512 + lane * 8;
      const unsigned short* c4 = CWl + (0 * 32 + wave * 4 + 0) * 512 + lane * 8;
      GLOAD_LDS16(b4, BstW + 4096);
      GLOAD_LDS16(c4, BstW + 4608);
      GLOAD_LDS16(b4 + 512, BstW + 5120);
      GLOAD_LDS16(c4 + 512, BstW + 5632);
    }
    VMCNT12;
    __builtin_amdgcn_sched_barrier(0);
    __builtin_amdgcn_s_barrier();   // A (and H writes) visible block-wide

    // ---- GEMM1: htmp = tanh(aggx @ gatW + gb); wave w -> col-tile w
    f32x4 acc1 = (f32x4){0.f, 0.f, 0.f, 0.f};
    VMCNT8;   // slot0 ready
    #pragma unroll
    for (int kt = 0; kt < 2; kt++) {
      int asw = nl * 128 + ((((kt << 2) + quad) ^ (nl & 7)) << 3);
      bf16x8 ah = *(const bf16x8*)(Ah + asw);
      bf16x8 al = *(const bf16x8*)(Al + asw);
      bf16x8 bh = *(const bf16x8*)(BstW + kt * 1024 + lane * 8);
      bf16x8 bl = *(const bf16x8*)(BstW + kt * 1024 + 512 + lane * 8);
      MFMA3(acc1, ah, al, bh, bl);
    }
    {  // stage G2 unit1 (kt'=0, gh=1) -> slot0
      const unsigned short* b = CWh + (0 * 32 + wave * 4 + 2) * 512 + lane * 8;
      const unsigned short* c = CWl + (0 * 32 + wave * 4 + 2) * 512 + lane * 8;
      GLOAD_LDS16(b, BstW);
      GLOAD_LDS16(c, BstW + 512);
      GLOAD_LDS16(b + 512, BstW + 1024);
      GLOAD_LDS16(c + 512, BstW + 1536);
    }
    VMCNT8;   // slot1 ready
    #pragma unroll
    for (int kt = 2; kt < 4; kt++) {
      int asw = nl * 128 + ((((kt << 2) + quad) ^ (nl & 7)) << 3);
      bf16x8 ah = *(const bf16x8*)(Ah + asw);
      bf16x8 al = *(const bf16x8*)(Al + asw);
      bf16x8 bh = *(const bf16x8*)(BstW + 2048 + (kt - 2) * 1024 + lane * 8);
      bf16x8 bl = *(const bf16x8*)(BstW + 2048 + (kt - 2) * 1024 + 512 + lane * 8);
      MFMA3(acc1, ah, al, bh, bl);
    }
    {  // stage G2 unit2 (kt'=1, gh=0) -> slot1
      const unsigned short* b = CWh + (1 * 32 + wave * 4 + 0) * 512 + lane * 8;
      const unsigned short* c = CWl + (1 * 32 + wave * 4 + 0) * 512 + lane * 8;
      GLOAD_LDS16(b, BstW + 2048);
      GLOAD_LDS16(c, BstW + 2560);
      GLOAD_LDS16(b + 512, BstW + 3072);
      GLOAD_LDS16(c + 512, BstW + 3584);
    }

    // T epilogue: tanh + bf16 split into swizzled T
    #pragma unroll
    for (int r = 0; r < 4; r++) {
      int rl = quad * 4 + r;
      float v = tanhf(acc1[r] + gbv);
      unsigned short vh, vl2;
      split_rne(v, vh, vl2);
      int addr = rl * 128 + ((fc ^ (rl & 7)) << 3) + fe;
      Th_[addr] = vh;
      Tl_[addr] = vl2;
    }
    LGKM0;
    __builtin_amdgcn_s_barrier();   // T visible; B-gloads stay in flight

    // prefetch next hop's aggx into A (counted in the stream; retire-order safe)
    if (hop < 2) {
      GLOAD_LDS16((hiArr ? aggxh : aggxl) + (size_t)(hop + 1) * NB * H + asrc,
                  (hiArr ? Ah : Al) + aj * 512);
    }

    // ---- GEMM2 stream: units u = 2kt (g0,g1), 2kt+1 (g2,g3); slot(u)=(u+2)%3
    #pragma unroll
    for (int g = 0; g < 4; g++) acc2[g] = (f32x4){0.f, 0.f, 0.f, 0.f};

    for (int kt = 0; kt < KT - 1; kt++) {
      // A fragment for this kt
      const unsigned short *pAh, *pAl;
      int kk;
      if (kt < 4)      { pAh = Th_; pAl = Tl_; kk = kt; }
      else if (kt < 8) { pAh = (hop == 0) ? A2h : Hh_;
                         pAl = (hop == 0) ? A2l : Hl_; kk = kt - 4; }
      else             { pAh = Hh_; pAl = Hl_; kk = kt - 8; }
      int asw = nl * 128 + ((((kk << 2) + quad) ^ (nl & 7)) << 3);
      bf16x8 ah = *(const bf16x8*)(pAh + asw);
      bf16x8 al = *(const bf16x8*)(pAl + asw);

      int u = 2 * kt;
      int s0 = (u + 2) % 3;
      VMCNT8;
      {
        unsigned short* sb = BstW + s0 * 2048;
        bf16x8 b0h = *(const bf16x8*)(sb + lane * 8);
        bf16x8 b0l = *(const bf16x8*)(sb + 512 + lane * 8);
        bf16x8 b1h = *(const bf16x8*)(sb + 1024 + lane * 8);
        bf16x8 b1l = *(const bf16x8*)(sb + 1536 + lane * 8);
        MFMA3(acc2[0], ah, al, b0h, b0l);
        MFMA3(acc2[1], ah, al, b1h, b1l);
      }
      {  // stage unit u+3 = (kt+1, gh=1) -> slot s0 (just freed)
        const unsigned short* b = CWh + ((kt + 1) * 32 + wave * 4 + 2) * 512 + lane * 8;
        const unsigned short* c = CWl + ((kt + 1) * 32 + wave * 4 + 2) * 512 + lane * 8;
        unsigned short* d = BstW + s0 * 2048;
        GLOAD_LDS16(b, d);
        GLOAD_LDS16(c, d + 512);
        GLOAD_LDS16(b + 512, d + 1024);
        GLOAD_LDS16(c + 512, d + 1536);
      }
      int s1 = (u + 3) % 3;
      VMCNT8;
      {
        unsigned short* sb = BstW + s1 * 2048;
        bf16x8 b0h = *(const bf16x8*)(sb + lane * 8);
        bf16x8 b0l = *(const bf16x8*)(sb + 512 + lane * 8);
        bf16x8 b1h = *(const bf16x8*)(sb + 1024 + lane * 8);
        bf16x8 b1l = *(const bf16x8*)(sb + 1536 + lane * 8);
        MFMA3(acc2[2], ah, al, b0h, b0l);
        MFMA3(acc2[3], ah, al, b1h, b1l);
      }
      if (kt < KT - 2) {  // stage unit u+4 = (kt+2, gh=0) -> slot s1
        const unsigned short* b = CWh + ((kt + 2) * 32 + wave * 4 + 0) * 512 + lane * 8;
        const unsigned short* c = CWl + ((kt + 2) * 32 + wave * 4 + 0) * 512 + lane * 8;
        unsigned short* d = BstW + s1 * 2048;
        GLOAD_LDS16(b, d);
        GLOAD_LDS16(c, d + 512);
        GLOAD_LDS16(b + 512, d + 1024);
        GLOAD_LDS16(c + 512, d + 1536);
      }
    }
    {  // peeled last kt: vmcnt(4) then vmcnt(0)
      int kt = KT - 1;
      const unsigned short *pAh, *pAl;
      int kk;
      if (kt < 4)      { pAh = Th_; pAl = Tl_; kk = kt; }
      else if (kt < 8) { pAh = (hop == 0) ? A2h : Hh_;
                         pAl = (hop == 0) ? A2l : Hl_; kk = kt - 4; }
      else             { pAh = Hh_; pAl = Hl_; kk = kt - 8; }
      int asw = nl * 128 + ((((kk << 2) + quad) ^ (nl & 7)) << 3);
      bf16x8 ah = *(const bf16x8*)(pAh + asw);
      bf16x8 al = *(const bf16x8*)(pAl + asw);
      int u = 2 * kt;
      int s0 = (u + 2) % 3, s1 = (u + 3) % 3;
      VMCNT4;
      {
        unsigned short* sb = BstW + s0 * 2048;
        bf16x8 b0h = *(const bf16x8*)(sb + lane * 8);
        bf16x8 b0l = *(const bf16x8*)(sb + 512 + lane * 8);
        bf16x8 b1h = *(const bf16x8*)(sb + 1024 + lane * 8);
        bf16x8 b1l = *(const bf16x8*)(sb + 1536 + lane * 8);
        MFMA3(acc2[0], ah, al, b0h, b0l);
        MFMA3(acc2[1], ah, al, b1h, b1l);
      }
      VMCNT0;
      {
        unsigned short* sb = BstW + s1 * 2048;
        bf16x8 b0h = *(const bf16x8*)(sb + lane * 8);
        bf16x8 b0l = *(const bf16x8*)(sb + 512 + lane * 8);
        bf16x8 b1h = *(const bf16x8*)(sb + 1024 + lane * 8);
        bf16x8 b1l = *(const bf16x8*)(sb + 1536 + lane * 8);
        MFMA3(acc2[2], ah, al, b0h, b0l);
        MFMA3(acc2[3], ah, al, b1h, b1l);
      }
    }
    LGKM0;
    __builtin_amdgcn_s_barrier();   // all H/T/X reads done before H rewrite

    // ---- LSTM pointwise; lane has all 4 gates of feature f
    #pragma unroll
    for (int r = 0; r < 4; r++) {
      int rl = quad * 4 + r;
      float gi = acc2[0][r] + b_i;
      float gf = acc2[1][r] + b_f;
      float gg = acc2[2][r] + b_g;
      float go = acc2[3][r] + b_o;
      float cn = sigmoidf_(gf) * creg[r] + sigmoidf_(gi) * tanhf(gg);
      float hn = sigmoidf_(go) * tanhf(cn);
      creg[r] = cn;
      unsigned short vh, vl2;
      split_rne(hn, vh, vl2);
      int addr = rl * 128 + ((fc ^ (rl & 7)) << 3) + fe;
      Hh_[addr] = vh;
      Hl_[addr] = vl2;
    }
  }
  LGKM0;
  __builtin_amdgcn_s_barrier();   // final H visible

  // ---- GEMM3: lin2 on final h; wave w -> col-tile w (2-slot mini pipeline)
  float l2bv = lin2_b[f];
  {
    const unsigned short* b0 = L2h + (0 * 8 + wave) * 512 + lane * 8;
    const unsigned short* c0 = L2l + (0 * 8 + wave) * 512 + lane * 8;
    GLOAD_LDS16(b0, BstW);
    GLOAD_LDS16(c0, BstW + 512);
    GLOAD_LDS16(b0 + 8 * 512, BstW + 1024);
    GLOAD_LDS16(c0 + 8 * 512, BstW + 1536);
    const unsigned short* b2 = L2h + (2 * 8 + wave) * 512 + lane * 8;
    const unsigned short* c2 = L2l + (2 * 8 + wave) * 512 + lane * 8;
    GLOAD_LDS16(b2, BstW + 2048);
    GLOAD_LDS16(c2, BstW + 2560);
    GLOAD_LDS16(b2 + 8 * 512, BstW + 3072);
    GLOAD_LDS16(c2 + 8 * 512, BstW + 3584);
  }
  f32x4 acc3 = (f32x4){0.f, 0.f, 0.f, 0.f};
  VMCNT4;
  #pragma unroll
  for (int kt = 0; kt < 2; kt++) {
    int asw = nl * 128 + ((((kt << 2) + quad) ^ (nl & 7)) << 3);
    bf16x8 ah = *(const bf16x8*)(Hh_ + asw);
    bf16x8 al = *(const bf16x8*)(Hl_ + asw);
    bf16x8 bh = *(const bf16x8*)(BstW + kt * 1024 + lane * 8);
    bf16x8 bl = *(const bf16x8*)(BstW + kt * 1024 + 512 + lane * 8);
    MFMA3(acc3, ah, al, bh, bl);
  }
  VMCNT0;
  #pragma unroll
  for (int kt = 2; kt < 4; kt++) {
    int asw = nl * 128 + ((((kt << 2) + quad) ^ (nl & 7)) << 3);
    bf16x8 ah = *(const bf16x8*)(Hh_ + asw);
    bf16x8 al = *(const bf16x8*)(Hl_ + asw);
    bf16x8 bh = *(const bf16x8*)(BstW + 2048 + (kt - 2) * 1024 + lane * 8);
    bf16x8 bl = *(const bf16x8*)(BstW + 2048 + (kt - 2) * 1024 + 512 + lane * 8);
    MFMA3(acc3, ah, al, bh, bl);
  }
  #pragma unroll
  for (int r = 0; r < 4; r++) {
    int row = r0 + quad * 4 + r;
    l2out[(size_t)row * H + f] = acc3[r] + l2bv;
  }
}

// ---------------- output gather ------------------------------------------------
__global__ void scatter_out(const float* __restrict__ l2out, const int* __restrict__ sel_map,
                            const int* __restrict__ root, const int* __restrict__ aggp,
                            float* __restrict__ out) {
  int id = blockIdx.x * 256 + threadIdx.x;
  if (id >= NB * H) return;
  int b = id >> 7, f = id & 127;
  int node = root[2 * b + (aggp[0] ? 0 : 1)];
  int c = sel_map[node];
  out[id] = l2out[(size_t)c * H + f];
}

// ==============================================================================
extern "C" void kernel_launch(void* const* d_in, const int* in_sizes, int n_in,
                              void* d_out, int out_size, void* d_ws, size_t ws_size,
                              hipStream_t stream) {
  const float* node_feat = (const float*)d_in[0];
  const float* send_embd = (const float*)d_in[1];
  const int*   edge_idx  = (const int*)d_in[2];
  const int*   root_idx  = (const int*)d_in[3];
  const int*   aggp      = (const int*)d_in[4];
  const float* lin1_W    = (const float*)d_in[5];
  const float* lin1_b    = (const float*)d_in[6];
  const float* gat_W     = (const float*)d_in[7];
  const float* gat_asrc  = (const float*)d_in[8];
  const float* gat_adst  = (const float*)d_in[9];
  const float* gat_b     = (const float*)d_in[10];
  const float* lstm_Wih  = (const float*)d_in[11];
  const float* lstm_Whh  = (const float*)d_in[12];
  const float* lstm_b    = (const float*)d_in[13];
  const float* lin2_W    = (const float*)d_in[14];
  const float* lin2_b    = (const float*)d_in[15];
  float* out = (float*)d_out;

  char* ws = (char*)d_ws;
  float* agg_raw = (float*)(ws + OFF_AGGRAW);
  float* wv2     = (float*)(ws + OFF_WV2);
  float* c2      = (float*)(ws + OFF_C2);
  int*   plist   = (int*)(ws + OFF_PLIST);
  float* s_src   = (float*)(ws + OFF_SSRC);
  float* s_dst   = (float*)(ws + OFF_SDST);
  float* wvec    = (float*)(ws + OFF_WVEC);
  int*   sel_map = (int*)(ws + OFF_SELMAP);
  int*   nodelst = (int*)(ws + OFF_NODELST);
  int*   cnt     = (int*)(ws + OFF_CNT);
  int*   deg     = (int*)(ws + OFF_DEG);
  int*   offs    = (int*)(ws + OFF_OFFS);
  int*   cursor  = (int*)(ws + OFF_CURSOR);
  int*   esort   = (int*)(ws + OFF_ESORT);
  unsigned short* aggxh = (unsigned short*)(ws + OFF_AGGXH);
  unsigned short* aggxl = (unsigned short*)(ws + OFF_AGGXL);
  unsigned short* xsh   = (unsigned short*)(ws + OFF_XSH);
  unsigned short* xsl   = (unsigned short*)(ws + OFF_XSL);
  float* l2out   = (float*)(ws + OFF_L2OUT);
  unsigned short* whi = (unsigned short*)(ws + OFF_WHI);
  unsigned short* wlo = (unsigned short*)(ws + OFF_WLO);

  // needed-row scratch carved from the aggx region: consumed by score_pass,
  // which runs strictly before gemm_unified writes aggxh/aggxl over it.
  int* need_flag = (int*)(ws + OFF_AGGXH);            // [N]
  int* need_list = need_flag + N;                     // [N]
  int* need_cnt  = cnt + 1;                           // zeroed by init_ws
  int* plist_cnt = cnt + 2;                           // zeroed by init_ws

  init_ws<<<512, 256, 0, stream>>>(sel_map, deg, cursor, cnt, need_flag);
  prep_kernel<<<6 + (WTOT + 255) / 256, 256, 0, stream>>>(
      gat_W, gat_asrc, gat_adst, wvec, lin1_W, lstm_Wih, lstm_Whh, lin2_W, whi, wlo);
  prep2_kernel<<<6, 256, 0, stream>>>(lin1_W, lin1_b, wvec, wv2, c2);
  roots_assign<<<(NB + 255) / 256, 256, 0, stream>>>(root_idx, aggp, sel_map, nodelst, cnt,
                                                     need_flag);

  // edge CSR: ONE full-E scan (count + pair compaction + need marking)
  const int egrid = (E + 256 * EPT - 1) / (256 * EPT);
  edge_pass1<<<egrid, 256, 0, stream>>>(edge_idx, sel_map, deg, plist, plist_cnt,
                                        need_flag);
  compact_need<<<(N + 255) / 256, 256, 0, stream>>>(need_flag, need_list, need_cnt);
  scan_kernel<<<1, 1024, 0, stream>>>(deg, offs);
  edge_pass2<<<256, 256, 0, stream>>>(plist, plist_cnt, offs, cursor, esort);

  // scores over needed rows (pure gather+dot; no lin1 GEMM over sources)
  score_pass<<<(N + 15) / 16, 256, 0, stream>>>(
      node_feat, send_embd, wv2, c2, s_src, s_dst, need_list, need_cnt);

  // raw-feature softmax aggregation per selected destination
  gat_node_kernel<<<NB, 256, 0, stream>>>(nodelst, cnt, offs, esort,
                                          node_feat, send_embd, s_src, s_dst, agg_raw);

  // one lin1 GEMM over 12288 agg rows + 4096 root rows
  gemm_unified<<<256, 256, 0, stream>>>(
      agg_raw, node_feat, send_embd, nodelst, cnt, offs,
      whi + WOFF_L1, wlo + WOFF_L1, lin1_b,
      aggxh, aggxl, xsh, xsl);

  // all 3 hops + lin2, fused, with pipelined-B counted-vmcnt schedule
  hops3_fused<<<NB / 16, 512, 0, stream>>>(
      aggxh, aggxl, xsh, xsl,
      whi + WOFF_GAT, wlo + WOFF_GAT, gat_b,
      whi + WOFF_CAT, wlo + WOFF_CAT, lstm_b,
      whi + WOFF_L2, wlo + WOFF_L2, lin2_b, l2out);

  scatter_out<<<(NB * H + 255) / 256, 256, 0, stream>>>(l2out, sel_map, root_idx, aggp, out);
}